// Round 1
// baseline (731.431 us; speedup 1.0000x reference)
//
#include <hip/hip_runtime.h>
#include <math.h>

#define NB 16
#define NA 64
#define NHD 128
#define NPAIR 2016
#define PSEL 256
#define NEL 128
// ws byte offsets (all 256-aligned)
#define WS_FLAG   0
#define WS_SUMW   1024
#define WS_SELJ   2048
#define WS_SELK   (WS_SELJ + 16384)
#define WS_SCAL   (WS_SELK + 16384)      // [4096][8] f32
#define WS_AE     (WS_SCAL + 131072)     // [128][128] f32
#define WS_GG     (WS_AE + 65536)        // [4096][64] f32
#define WS_A0     (WS_GG + 1048576)      // [4096][128] f32
#define WS_AGG    (WS_A0 + 2097152)      // [16][128][64] f32

__device__ __forceinline__ float siluf(float x) { return x / (1.0f + expf(-x)); }
__device__ __forceinline__ float cutf(float r) {
  return (r <= 6.0f) ? (0.5f * (cosf((3.14159265358979323846f * r) / 6.0f) + 1.0f)) : 0.0f;
}
__device__ __forceinline__ float rbff(float r, int i) {
  float rc = fminf(r, 6.0f);
  float c = (float)i * (6.0f / 31.0f);
  float d = rc - c;
  return expf(-26.694445f * d * d);
}
__device__ __forceinline__ void pair_jk(int p, int& j, int& k) {
  int jj = (int)((127.0 - sqrt(16129.0 - 8.0 * (double)p)) * 0.5);
  if (jj < 0) jj = 0;
  if (jj > 62) jj = 62;
  while (jj < 62 && (63 * (jj + 1) - ((jj + 1) * jj) / 2) <= p) jj++;
  while (jj > 0 && (63 * jj - (jj * (jj - 1)) / 2) > p) jj--;
  j = jj;
  k = p - (63 * jj - (jj * (jj - 1)) / 2) + jj + 1;
}

// detect int64-vs-int32 z layout: z values are >=1, so a zero at i32 index 1 => int64
__global__ void k0_flag(const int* __restrict__ z, int* __restrict__ flag) {
  if (threadIdx.x == 0) *flag = (z[1] == 0) ? 1 : 0;
}

// per-batch pair scoring + exact stable top-256 via bitonic sort of (score|idx) keys
__global__ __launch_bounds__(256) void k1_select(const float* __restrict__ pos, char* ws) {
#pragma clang fp contract(off)
  int b = blockIdx.x, t = threadIdx.x;
  __shared__ float px[64], py[64], pz[64], rr[64];
  __shared__ unsigned long long keys[2048];
  __shared__ float wred[256];
  if (t < 64) {
    px[t] = pos[(b * 64 + t) * 3 + 0];
    py[t] = pos[(b * 64 + t) * 3 + 1];
    pz[t] = pos[(b * 64 + t) * 3 + 2];
  }
  __syncthreads();
  if (t < 64) {
    float dx = px[t] - px[0], dy = py[t] - py[0], dz = pz[t] - pz[0];
    rr[t] = sqrtf((dx * dx + dy * dy) + dz * dz);
  }
  __syncthreads();
  for (int p = t; p < 2048; p += 256) {
    unsigned long long key = 0xFFFFFFFFFFFFFFFFull;
    if (p < NPAIR) {
      int j, k;
      pair_jk(p, j, k);
      bool vj = (j != 0) && (rr[j] <= 6.0f);
      bool vk = (rr[k] <= 6.0f);
      unsigned int sb = 0x7f800000u;  // +inf
      if (vj && vk) {
        float dx = px[k] - px[j], dy = py[k] - py[j], dz = pz[k] - pz[j];
        float rjk = sqrtf((dx * dx + dy * dy) + dz * dz);
        float score = (rr[j] + rr[k]) + 0.5f * rjk;
        sb = __float_as_uint(score);
      }
      key = (((unsigned long long)sb) << 32) | (unsigned int)p;
    }
    keys[p] = key;
  }
  __syncthreads();
  for (int kk = 2; kk <= 2048; kk <<= 1) {
    for (int jj = kk >> 1; jj > 0; jj >>= 1) {
      for (int i = t; i < 2048; i += 256) {
        int ixj = i ^ jj;
        if (ixj > i) {
          unsigned long long a = keys[i], c = keys[ixj];
          bool up = ((i & kk) == 0);
          bool sw = up ? (a > c) : (a < c);
          if (sw) { keys[i] = c; keys[ixj] = a; }
        }
      }
      __syncthreads();
    }
  }
  float myw = 0.0f;
  if (t < PSEL) {
    unsigned long long key = keys[t];
    unsigned int sb = (unsigned int)(key >> 32);
    int p = (int)(key & 0xFFFFFFFFu);
    bool pv = (sb < 0x7f800000u);
    int j = 0, k = 0;
    if (pv) pair_jk(p, j, k);
    float r0j = rr[j], r0k = rr[k];
    float vjx = px[j] - px[0], vjy = py[j] - py[0], vjz = pz[j] - pz[0];
    float vkx = px[k] - px[0], vky = py[k] - py[0], vkz = pz[k] - pz[0];
    float dx = px[k] - px[j], dy = py[k] - py[j], dz = pz[k] - pz[j];
    float rjk = sqrtf((dx * dx + dy * dy) + dz * dz);
    float ij = 1.0f / fmaxf(r0j, 1e-8f);
    float ik = 1.0f / fmaxf(r0k, 1e-8f);
    float cs = (vjx * vkx + vjy * vky + vjz * vkz) * ij * ik;
    cs = fminf(1.0f, fmaxf(-1.0f, cs));
    float w = pv ? (cutf(r0j) * cutf(r0k) * cutf(rjk)) : 0.0f;
    int* selJ = (int*)(ws + WS_SELJ);
    int* selK = (int*)(ws + WS_SELK);
    float* scal = (float*)(ws + WS_SCAL);
    selJ[b * PSEL + t] = j;
    selK[b * PSEL + t] = k;
    float* s = &scal[(b * PSEL + t) * 8];
    s[0] = r0j; s[1] = r0k; s[2] = rjk; s[3] = cs; s[4] = w;
    myw = w;
  }
  wred[t] = myw;
  __syncthreads();
  for (int s2 = 128; s2 > 0; s2 >>= 1) {
    if (t < s2) wred[t] += wred[t + s2];
    __syncthreads();
  }
  if (t == 0) ((float*)(ws + WS_SUMW))[b] = fmaxf(wred[0], 1e-8f);
}

// Ae[e][d] = e_feat[e] @ pw0[64:96]
__global__ __launch_bounds__(128) void k2a_ae(const float* __restrict__ ef,
                                              const float* __restrict__ pw0, char* ws) {
  int e = blockIdx.x, d = threadIdx.x;
  float* Ae = (float*)(ws + WS_AE);
  __shared__ float er[32];
  if (d < 32) er[d] = ef[e * 32 + d];
  __syncthreads();
  float a = 0.0f;
  for (int i = 0; i < 32; i++) a += er[i] * pw0[(64 + i) * 128 + d];
  Ae[e * 128 + d] = a;
}

// A0[b,p][d] = z_emb[zj]@pw0[0:32] + z_emb[zk]@pw0[32:64] + pb0
__global__ __launch_bounds__(128) void k2b_a0(const int* __restrict__ z,
                                              const float* __restrict__ zemb,
                                              const float* __restrict__ pw0,
                                              const float* __restrict__ pb0, char* ws) {
  int p = blockIdx.x, b = blockIdx.y, d = threadIdx.x;
  const int* selJ = (const int*)(ws + WS_SELJ);
  const int* selK = (const int*)(ws + WS_SELK);
  int is64 = *((const int*)(ws + WS_FLAG));
  float* A0 = (float*)(ws + WS_A0);
  int j = selJ[b * PSEL + p], k = selK[b * PSEL + p];
  __shared__ float zr[64];
  if (d < 64) {
    int atom = (d < 32) ? j : k;
    int zi = b * 64 + atom;
    int zv = is64 ? z[zi * 2] : z[zi];
    zr[d] = zemb[zv * 32 + (d & 31)];
  }
  __syncthreads();
  float a = pb0[d];
  for (int i = 0; i < 32; i++) {
    a += zr[i] * pw0[i * 128 + d];
    a += zr[32 + i] * pw0[(32 + i) * 128 + d];
  }
  A0[(b * PSEL + p) * 128 + d] = a;
}

// geom MLP 353->256->256->64, folds w/sumw into gg
__global__ __launch_bounds__(256) void k3_geom(const float* __restrict__ h,
    const float* __restrict__ gw0, const float* __restrict__ gb0,
    const float* __restrict__ gw1, const float* __restrict__ gb1,
    const float* __restrict__ gw2, const float* __restrict__ gb2, char* ws) {
  int blk = blockIdx.x;
  int b = blk >> 4, p0 = (blk & 15) * 16;
  int t = threadIdx.x;
  const int* selJ = (const int*)(ws + WS_SELJ);
  const int* selK = (const int*)(ws + WS_SELK);
  const float* scal = (const float*)(ws + WS_SCAL);
  const float* sumw = (const float*)(ws + WS_SUMW);
  float* gg = (float*)(ws + WS_GG);
  __shared__ float xT[353][16];
  __shared__ float x1T[256][16];
  __shared__ float x2T[256][16];
  {
    int row = t & 15, fs = t >> 4;
    int p = p0 + row;
    int j = selJ[b * PSEL + p], k = selK[b * PSEL + p];
    const float* s = &scal[(b * PSEL + p) * 8];
    float r0j = s[0], r0k = s[1], rjk = s[2], cs = s[3];
    for (int f = fs; f < 353; f += 16) {
      float v;
      if (f < 128) v = h[(b * 64 + j) * 128 + f];
      else if (f < 256) v = h[(b * 64 + k) * 128 + (f - 128)];
      else if (f < 288) v = rbff(r0j, f - 256);
      else if (f < 320) v = rbff(r0k, f - 288);
      else if (f < 352) v = rbff(rjk, f - 320);
      else v = cs;
      xT[f][row] = v;
    }
  }
  __syncthreads();
  {  // L1: 16x256 K=353
    int r0 = (t & 3) * 4, c0 = (t >> 2) * 4;
    float acc[4][4] = {};
    for (int k2 = 0; k2 < 353; k2++) {
      float4 xv = *(const float4*)&xT[k2][r0];
      float4 wv = *(const float4*)&gw0[k2 * 256 + c0];
      float xs[4] = {xv.x, xv.y, xv.z, xv.w};
      float wss[4] = {wv.x, wv.y, wv.z, wv.w};
#pragma unroll
      for (int i = 0; i < 4; i++)
#pragma unroll
        for (int j2 = 0; j2 < 4; j2++) acc[i][j2] += xs[i] * wss[j2];
    }
#pragma unroll
    for (int jj = 0; jj < 4; jj++) {
      float bias = gb0[c0 + jj];
#pragma unroll
      for (int i = 0; i < 4; i++) x1T[c0 + jj][r0 + i] = siluf(acc[i][jj] + bias);
    }
  }
  __syncthreads();
  {  // L2: 16x256 K=256
    int r0 = (t & 3) * 4, c0 = (t >> 2) * 4;
    float acc[4][4] = {};
    for (int k2 = 0; k2 < 256; k2++) {
      float4 xv = *(const float4*)&x1T[k2][r0];
      float4 wv = *(const float4*)&gw1[k2 * 256 + c0];
      float xs[4] = {xv.x, xv.y, xv.z, xv.w};
      float wss[4] = {wv.x, wv.y, wv.z, wv.w};
#pragma unroll
      for (int i = 0; i < 4; i++)
#pragma unroll
        for (int j2 = 0; j2 < 4; j2++) acc[i][j2] += xs[i] * wss[j2];
    }
#pragma unroll
    for (int jj = 0; jj < 4; jj++) {
      float bias = gb1[c0 + jj];
#pragma unroll
      for (int i = 0; i < 4; i++) x2T[c0 + jj][r0 + i] = siluf(acc[i][jj] + bias);
    }
  }
  __syncthreads();
  {  // L3: 16x64 K=256 (linear) + fold w/norm
    int r0 = (t & 3) * 4, c = t >> 2;
    float acc[4] = {};
    for (int k2 = 0; k2 < 256; k2++) {
      float4 xv = *(const float4*)&x2T[k2][r0];
      float wv = gw2[k2 * 64 + c];
      acc[0] += xv.x * wv; acc[1] += xv.y * wv; acc[2] += xv.z * wv; acc[3] += xv.w * wv;
    }
    float snorm = sumw[b];
    float bias = gb2[c];
#pragma unroll
    for (int i = 0; i < 4; i++) {
      int p = p0 + r0 + i;
      float w = scal[(b * PSEL + p) * 8 + 4];
      gg[(b * PSEL + p) * 64 + c] = (acc[i] + bias) * (w / snorm);
    }
  }
}

// fused elem MLP (128->128 silu ->64) + weighted aggregation over p
__global__ __launch_bounds__(256, 2) void k4_elem(
    const float* __restrict__ pw1, const float* __restrict__ pb1,
    const float* __restrict__ pw2, const float* __restrict__ pb2, char* ws) {
  int pc = blockIdx.x, et = blockIdx.y, b = blockIdx.z;
  int t = threadIdx.x;
  const float* A0 = (const float*)(ws + WS_A0);
  const float* Ae = (const float*)(ws + WS_AE);
  const float* gg = (const float*)(ws + WS_GG);
  float* agg = (float*)(ws + WS_AGG);
  __shared__ float x0T[128][64];
  __shared__ float x1T[128][64];
  int e0 = et * 8;
  int rt = t & 7, ct = t >> 3;
  int dd = ct * 2;
  float aggAcc0 = 0.0f, aggAcc1 = 0.0f;
  for (int g2 = 0; g2 < 8; g2++) {
    int pbase = pc * 64 + g2 * 8;
    __syncthreads();
    // phase A: x0T[k][e*8+pl] = silu(A0[p][k] + Ae[e0+e][k])
    for (int ii = 0; ii < 32; ii++) {
      int idx = t + 256 * ii;
      int k2 = idx >> 6, r = idx & 63;
      int e = r >> 3, pl = r & 7;
      float v = A0[(b * PSEL + pbase + pl) * 128 + k2] + Ae[(e0 + e) * 128 + k2];
      x0T[k2][r] = siluf(v);
    }
    __syncthreads();
    // phase B: layer1 GEMM 64x128 K=128, thread tile 8r x 4c
    float acc[8][4] = {};
    int c0 = ct * 4;
    for (int k2 = 0; k2 < 128; k2++) {
      float4 xa = *(const float4*)&x0T[k2][rt * 8];
      float4 xb = *(const float4*)&x0T[k2][rt * 8 + 4];
      float4 wv = *(const float4*)&pw1[k2 * 128 + c0];
      float xs[8] = {xa.x, xa.y, xa.z, xa.w, xb.x, xb.y, xb.z, xb.w};
      float wss[4] = {wv.x, wv.y, wv.z, wv.w};
#pragma unroll
      for (int i = 0; i < 8; i++)
#pragma unroll
        for (int j2 = 0; j2 < 4; j2++) acc[i][j2] += xs[i] * wss[j2];
    }
#pragma unroll
    for (int jj = 0; jj < 4; jj++) {
      float bias = pb1[c0 + jj];
      float4 o0, o1;
      o0.x = siluf(acc[0][jj] + bias); o0.y = siluf(acc[1][jj] + bias);
      o0.z = siluf(acc[2][jj] + bias); o0.w = siluf(acc[3][jj] + bias);
      o1.x = siluf(acc[4][jj] + bias); o1.y = siluf(acc[5][jj] + bias);
      o1.z = siluf(acc[6][jj] + bias); o1.w = siluf(acc[7][jj] + bias);
      *(float4*)&x1T[c0 + jj][rt * 8] = o0;
      *(float4*)&x1T[c0 + jj][rt * 8 + 4] = o1;
    }
    __syncthreads();
    // phase C: layer2 64x64 K=128, thread tile 8r(one e) x 2d, weighted agg
    float a2[8][2] = {};
    for (int k2 = 0; k2 < 128; k2++) {
      float4 xa = *(const float4*)&x1T[k2][rt * 8];
      float4 xb = *(const float4*)&x1T[k2][rt * 8 + 4];
      float2 wv = *(const float2*)&pw2[k2 * 64 + dd];
      float xs[8] = {xa.x, xa.y, xa.z, xa.w, xb.x, xb.y, xb.z, xb.w};
#pragma unroll
      for (int i = 0; i < 8; i++) {
        a2[i][0] += xs[i] * wv.x;
        a2[i][1] += xs[i] * wv.y;
      }
    }
    float b0v = pb2[dd], b1v = pb2[dd + 1];
#pragma unroll
    for (int pl = 0; pl < 8; pl++) {
      const float* gp = &gg[(b * PSEL + pbase + pl) * 64 + dd];
      aggAcc0 += gp[0] * (a2[pl][0] + b0v);
      aggAcc1 += gp[1] * (a2[pl][1] + b1v);
    }
  }
  int e = e0 + rt;
  atomicAdd(&agg[(b * NEL + e) * 64 + dd], aggAcc0);
  atomicAdd(&agg[(b * NEL + e) * 64 + dd + 1], aggAcc1);
}

// output MLP 64->256 silu ->128
__global__ __launch_bounds__(256) void k5_out(
    const float* __restrict__ ow0, const float* __restrict__ ob0,
    const float* __restrict__ ow1, const float* __restrict__ ob1,
    const char* ws, float* __restrict__ out) {
  int row0 = blockIdx.x * 16;  // rows over (b*128+e), 2048 total
  int t = threadIdx.x;
  const float* agg = (const float*)(ws + WS_AGG);
  __shared__ float xT[64][16];
  __shared__ float x1T[256][16];
  {
    int row = t & 15, fs = t >> 4;
    for (int f = fs; f < 64; f += 16) xT[f][row] = agg[(row0 + row) * 64 + f];
  }
  __syncthreads();
  {  // L1: 16x256 K=64
    int r0 = (t & 3) * 4, c0 = (t >> 2) * 4;
    float acc[4][4] = {};
    for (int k2 = 0; k2 < 64; k2++) {
      float4 xv = *(const float4*)&xT[k2][r0];
      float4 wv = *(const float4*)&ow0[k2 * 256 + c0];
      float xs[4] = {xv.x, xv.y, xv.z, xv.w};
      float wss[4] = {wv.x, wv.y, wv.z, wv.w};
#pragma unroll
      for (int i = 0; i < 4; i++)
#pragma unroll
        for (int j2 = 0; j2 < 4; j2++) acc[i][j2] += xs[i] * wss[j2];
    }
#pragma unroll
    for (int jj = 0; jj < 4; jj++) {
      float bias = ob0[c0 + jj];
#pragma unroll
      for (int i = 0; i < 4; i++) x1T[c0 + jj][r0 + i] = siluf(acc[i][jj] + bias);
    }
  }
  __syncthreads();
  {  // L2: 16x128 K=256 (linear), write out
    int r0 = (t & 3) * 4, c0 = (t >> 2) * 2;
    float acc[4][2] = {};
    for (int k2 = 0; k2 < 256; k2++) {
      float4 xv = *(const float4*)&x1T[k2][r0];
      float2 wv = *(const float2*)&ow1[k2 * 128 + c0];
      float xs[4] = {xv.x, xv.y, xv.z, xv.w};
#pragma unroll
      for (int i = 0; i < 4; i++) {
        acc[i][0] += xs[i] * wv.x;
        acc[i][1] += xs[i] * wv.y;
      }
    }
#pragma unroll
    for (int i = 0; i < 4; i++)
#pragma unroll
      for (int j2 = 0; j2 < 2; j2++)
        out[(row0 + r0 + i) * 128 + c0 + j2] = acc[i][j2] + ob1[c0 + j2];
  }
}

extern "C" void kernel_launch(void* const* d_in, const int* in_sizes, int n_in,
                              void* d_out, int out_size, void* d_ws, size_t ws_size,
                              hipStream_t stream) {
  const float* h     = (const float*)d_in[0];
  const int*   z     = (const int*)d_in[1];
  const float* pos   = (const float*)d_in[2];
  const float* efeat = (const float*)d_in[4];
  const float* zemb  = (const float*)d_in[5];
  const float* pw0 = (const float*)d_in[6];
  const float* pb0 = (const float*)d_in[7];
  const float* pw1 = (const float*)d_in[8];
  const float* pb1 = (const float*)d_in[9];
  const float* pw2 = (const float*)d_in[10];
  const float* pb2 = (const float*)d_in[11];
  const float* gw0 = (const float*)d_in[12];
  const float* gb0 = (const float*)d_in[13];
  const float* gw1 = (const float*)d_in[14];
  const float* gb1 = (const float*)d_in[15];
  const float* gw2 = (const float*)d_in[16];
  const float* gb2 = (const float*)d_in[17];
  const float* ow0 = (const float*)d_in[18];
  const float* ob0 = (const float*)d_in[19];
  const float* ow1 = (const float*)d_in[20];
  const float* ob1 = (const float*)d_in[21];
  char* ws = (char*)d_ws;
  float* out = (float*)d_out;

  hipMemsetAsync(ws + WS_AGG, 0, NB * NEL * 64 * sizeof(float), stream);
  k0_flag<<<1, 64, 0, stream>>>(z, (int*)(ws + WS_FLAG));
  k1_select<<<16, 256, 0, stream>>>(pos, ws);
  k2a_ae<<<128, 128, 0, stream>>>(efeat, pw0, ws);
  k2b_a0<<<dim3(256, 16), 128, 0, stream>>>(z, zemb, pw0, pb0, ws);
  k3_geom<<<256, 256, 0, stream>>>(h, gw0, gb0, gw1, gb1, gw2, gb2, ws);
  k4_elem<<<dim3(4, 16, 16), 256, 0, stream>>>(pw1, pb1, pw2, pb2, ws);
  k5_out<<<128, 256, 0, stream>>>(ow0, ob0, ow1, ob1, ws, out);
}

// Round 2
// 387.355 us; speedup vs baseline: 1.8883x; 1.8883x over previous
//
#include <hip/hip_runtime.h>
#include <math.h>

#define NB 16
#define NA 64
#define NHD 128
#define NPAIR 2016
#define PSEL 256
#define NEL 128
// ws byte offsets (all 256-aligned)
#define WS_FLAG   0
#define WS_SUMW   1024
#define WS_SELJ   2048
#define WS_SELK   (WS_SELJ + 16384)
#define WS_SCAL   (WS_SELK + 16384)      // [4096][8] f32
#define WS_AE     (WS_SCAL + 131072)     // [128][128] f32
#define WS_GG     (WS_AE + 65536)        // [4096][64] f32
#define WS_A0     (WS_GG + 1048576)      // [4096][128] f32
#define WS_AGG    (WS_A0 + 2097152)      // [16][128][64] f32
#define WS_W1F    (WS_AGG + 524288)      // bf16 frag-swizzled pw1, 32KB
#define WS_W2F    (WS_W1F + 32768)       // bf16 frag-swizzled pw2, 16KB

typedef short v8s __attribute__((ext_vector_type(8)));
typedef float v4f __attribute__((ext_vector_type(4)));

__device__ __forceinline__ float siluf(float x) { return x / (1.0f + expf(-x)); }
__device__ __forceinline__ float siluf_fast(float x) { return x / (1.0f + __expf(-x)); }
__device__ __forceinline__ unsigned short f2bf(float f) {
  unsigned int u = __float_as_uint(f);
  return (unsigned short)((u + 0x7fffu + ((u >> 16) & 1u)) >> 16);
}
__device__ __forceinline__ float cutf(float r) {
  return (r <= 6.0f) ? (0.5f * (cosf((3.14159265358979323846f * r) / 6.0f) + 1.0f)) : 0.0f;
}
__device__ __forceinline__ float rbff(float r, int i) {
  float rc = fminf(r, 6.0f);
  float c = (float)i * (6.0f / 31.0f);
  float d = rc - c;
  return expf(-26.694445f * d * d);
}
__device__ __forceinline__ void pair_jk(int p, int& j, int& k) {
  int jj = (int)((127.0 - sqrt(16129.0 - 8.0 * (double)p)) * 0.5);
  if (jj < 0) jj = 0;
  if (jj > 62) jj = 62;
  while (jj < 62 && (63 * (jj + 1) - ((jj + 1) * jj) / 2) <= p) jj++;
  while (jj > 0 && (63 * jj - (jj * (jj - 1)) / 2) > p) jj--;
  j = jj;
  k = p - (63 * jj - (jj * (jj - 1)) / 2) + jj + 1;
}

// detect int64-vs-int32 z layout: z values are >=1, so a zero at i32 index 1 => int64
__global__ void k0_flag(const int* __restrict__ z, int* __restrict__ flag) {
  if (threadIdx.x == 0) *flag = (z[1] == 0) ? 1 : 0;
}

// per-batch pair scoring + exact stable top-256 via bitonic sort of (score|idx) keys
__global__ __launch_bounds__(256) void k1_select(const float* __restrict__ pos, char* ws) {
#pragma clang fp contract(off)
  int b = blockIdx.x, t = threadIdx.x;
  __shared__ float px[64], py[64], pz[64], rr[64];
  __shared__ unsigned long long keys[2048];
  __shared__ float wred[256];
  if (t < 64) {
    px[t] = pos[(b * 64 + t) * 3 + 0];
    py[t] = pos[(b * 64 + t) * 3 + 1];
    pz[t] = pos[(b * 64 + t) * 3 + 2];
  }
  __syncthreads();
  if (t < 64) {
    float dx = px[t] - px[0], dy = py[t] - py[0], dz = pz[t] - pz[0];
    rr[t] = sqrtf((dx * dx + dy * dy) + dz * dz);
  }
  __syncthreads();
  for (int p = t; p < 2048; p += 256) {
    unsigned long long key = 0xFFFFFFFFFFFFFFFFull;
    if (p < NPAIR) {
      int j, k;
      pair_jk(p, j, k);
      bool vj = (j != 0) && (rr[j] <= 6.0f);
      bool vk = (rr[k] <= 6.0f);
      unsigned int sb = 0x7f800000u;  // +inf
      if (vj && vk) {
        float dx = px[k] - px[j], dy = py[k] - py[j], dz = pz[k] - pz[j];
        float rjk = sqrtf((dx * dx + dy * dy) + dz * dz);
        float score = (rr[j] + rr[k]) + 0.5f * rjk;
        sb = __float_as_uint(score);
      }
      key = (((unsigned long long)sb) << 32) | (unsigned int)p;
    }
    keys[p] = key;
  }
  __syncthreads();
  for (int kk = 2; kk <= 2048; kk <<= 1) {
    for (int jj = kk >> 1; jj > 0; jj >>= 1) {
      for (int i = t; i < 2048; i += 256) {
        int ixj = i ^ jj;
        if (ixj > i) {
          unsigned long long a = keys[i], c = keys[ixj];
          bool up = ((i & kk) == 0);
          bool sw = up ? (a > c) : (a < c);
          if (sw) { keys[i] = c; keys[ixj] = a; }
        }
      }
      __syncthreads();
    }
  }
  float myw = 0.0f;
  if (t < PSEL) {
    unsigned long long key = keys[t];
    unsigned int sb = (unsigned int)(key >> 32);
    int p = (int)(key & 0xFFFFFFFFu);
    bool pv = (sb < 0x7f800000u);
    int j = 0, k = 0;
    if (pv) pair_jk(p, j, k);
    float r0j = rr[j], r0k = rr[k];
    float vjx = px[j] - px[0], vjy = py[j] - py[0], vjz = pz[j] - pz[0];
    float vkx = px[k] - px[0], vky = py[k] - py[0], vkz = pz[k] - pz[0];
    float dx = px[k] - px[j], dy = py[k] - py[j], dz = pz[k] - pz[j];
    float rjk = sqrtf((dx * dx + dy * dy) + dz * dz);
    float ij = 1.0f / fmaxf(r0j, 1e-8f);
    float ik = 1.0f / fmaxf(r0k, 1e-8f);
    float cs = (vjx * vkx + vjy * vky + vjz * vkz) * ij * ik;
    cs = fminf(1.0f, fmaxf(-1.0f, cs));
    float w = pv ? (cutf(r0j) * cutf(r0k) * cutf(rjk)) : 0.0f;
    int* selJ = (int*)(ws + WS_SELJ);
    int* selK = (int*)(ws + WS_SELK);
    float* scal = (float*)(ws + WS_SCAL);
    selJ[b * PSEL + t] = j;
    selK[b * PSEL + t] = k;
    float* s = &scal[(b * PSEL + t) * 8];
    s[0] = r0j; s[1] = r0k; s[2] = rjk; s[3] = cs; s[4] = w;
    myw = w;
  }
  wred[t] = myw;
  __syncthreads();
  for (int s2 = 128; s2 > 0; s2 >>= 1) {
    if (t < s2) wred[t] += wred[t + s2];
    __syncthreads();
  }
  if (t == 0) ((float*)(ws + WS_SUMW))[b] = fmaxf(wred[0], 1e-8f);
}

// Ae[e][d] = e_feat[e] @ pw0[64:96]
__global__ __launch_bounds__(128) void k2a_ae(const float* __restrict__ ef,
                                              const float* __restrict__ pw0, char* ws) {
  int e = blockIdx.x, d = threadIdx.x;
  float* Ae = (float*)(ws + WS_AE);
  __shared__ float er[32];
  if (d < 32) er[d] = ef[e * 32 + d];
  __syncthreads();
  float a = 0.0f;
  for (int i = 0; i < 32; i++) a += er[i] * pw0[(64 + i) * 128 + d];
  Ae[e * 128 + d] = a;
}

// A0[b,p][d] = z_emb[zj]@pw0[0:32] + z_emb[zk]@pw0[32:64] + pb0
__global__ __launch_bounds__(128) void k2b_a0(const int* __restrict__ z,
                                              const float* __restrict__ zemb,
                                              const float* __restrict__ pw0,
                                              const float* __restrict__ pb0, char* ws) {
  int p = blockIdx.x, b = blockIdx.y, d = threadIdx.x;
  const int* selJ = (const int*)(ws + WS_SELJ);
  const int* selK = (const int*)(ws + WS_SELK);
  int is64 = *((const int*)(ws + WS_FLAG));
  float* A0 = (float*)(ws + WS_A0);
  int j = selJ[b * PSEL + p], k = selK[b * PSEL + p];
  __shared__ float zr[64];
  if (d < 64) {
    int atom = (d < 32) ? j : k;
    int zi = b * 64 + atom;
    int zv = is64 ? z[zi * 2] : z[zi];
    zr[d] = zemb[zv * 32 + (d & 31)];
  }
  __syncthreads();
  float a = pb0[d];
  for (int i = 0; i < 32; i++) {
    a += zr[i] * pw0[i * 128 + d];
    a += zr[32 + i] * pw0[(32 + i) * 128 + d];
  }
  A0[(b * PSEL + p) * 128 + d] = a;
}

// pre-swizzle pw1/pw2 into bf16 MFMA A-operand fragment order (A = W^T: A[n][k])
// W1F layout: [(nt*4+kk)*64 + lane]*8 + j  -> A[n=16nt+(lane&15)][k=32kk+(lane>>4)*8+j]
__global__ __launch_bounds__(256) void k2c_wfrag(const float* __restrict__ pw1,
                                                 const float* __restrict__ pw2, char* ws) {
  int idx = blockIdx.x * 256 + threadIdx.x;  // 0..24575
  unsigned short* W1F = (unsigned short*)(ws + WS_W1F);
  unsigned short* W2F = (unsigned short*)(ws + WS_W2F);
  if (idx < 16384) {
    int j = idx & 7, l = (idx >> 3) & 63, t2 = idx >> 9;  // t2 = nt*4+kk, 0..31
    int kk = t2 & 3, nt = t2 >> 2;
    int n = 16 * nt + (l & 15), k = 32 * kk + (l >> 4) * 8 + j;
    W1F[idx] = f2bf(pw1[k * 128 + n]);
  } else if (idx < 24576) {
    int id2 = idx - 16384;
    int j = id2 & 7, l = (id2 >> 3) & 63, t2 = id2 >> 9;  // 0..15
    int kk = t2 & 3, nt = t2 >> 2;
    int n = 16 * nt + (l & 15), k = 32 * kk + (l >> 4) * 8 + j;
    W2F[id2] = f2bf(pw2[k * 64 + n]);
  }
}

// geom MLP 353->256->256->64, folds w/sumw into gg
__global__ __launch_bounds__(256) void k3_geom(const float* __restrict__ h,
    const float* __restrict__ gw0, const float* __restrict__ gb0,
    const float* __restrict__ gw1, const float* __restrict__ gb1,
    const float* __restrict__ gw2, const float* __restrict__ gb2, char* ws) {
  int blk = blockIdx.x;
  int b = blk >> 4, p0 = (blk & 15) * 16;
  int t = threadIdx.x;
  const int* selJ = (const int*)(ws + WS_SELJ);
  const int* selK = (const int*)(ws + WS_SELK);
  const float* scal = (const float*)(ws + WS_SCAL);
  const float* sumw = (const float*)(ws + WS_SUMW);
  float* gg = (float*)(ws + WS_GG);
  __shared__ float xT[353][16];
  __shared__ float x1T[256][16];
  __shared__ float x2T[256][16];
  {
    int row = t & 15, fs = t >> 4;
    int p = p0 + row;
    int j = selJ[b * PSEL + p], k = selK[b * PSEL + p];
    const float* s = &scal[(b * PSEL + p) * 8];
    float r0j = s[0], r0k = s[1], rjk = s[2], cs = s[3];
    for (int f = fs; f < 353; f += 16) {
      float v;
      if (f < 128) v = h[(b * 64 + j) * 128 + f];
      else if (f < 256) v = h[(b * 64 + k) * 128 + (f - 128)];
      else if (f < 288) v = rbff(r0j, f - 256);
      else if (f < 320) v = rbff(r0k, f - 288);
      else if (f < 352) v = rbff(rjk, f - 320);
      else v = cs;
      xT[f][row] = v;
    }
  }
  __syncthreads();
  {  // L1: 16x256 K=353
    int r0 = (t & 3) * 4, c0 = (t >> 2) * 4;
    float acc[4][4] = {};
    for (int k2 = 0; k2 < 353; k2++) {
      float4 xv = *(const float4*)&xT[k2][r0];
      float4 wv = *(const float4*)&gw0[k2 * 256 + c0];
      float xs[4] = {xv.x, xv.y, xv.z, xv.w};
      float wss[4] = {wv.x, wv.y, wv.z, wv.w};
#pragma unroll
      for (int i = 0; i < 4; i++)
#pragma unroll
        for (int j2 = 0; j2 < 4; j2++) acc[i][j2] += xs[i] * wss[j2];
    }
#pragma unroll
    for (int jj = 0; jj < 4; jj++) {
      float bias = gb0[c0 + jj];
#pragma unroll
      for (int i = 0; i < 4; i++) x1T[c0 + jj][r0 + i] = siluf(acc[i][jj] + bias);
    }
  }
  __syncthreads();
  {  // L2: 16x256 K=256
    int r0 = (t & 3) * 4, c0 = (t >> 2) * 4;
    float acc[4][4] = {};
    for (int k2 = 0; k2 < 256; k2++) {
      float4 xv = *(const float4*)&x1T[k2][r0];
      float4 wv = *(const float4*)&gw1[k2 * 256 + c0];
      float xs[4] = {xv.x, xv.y, xv.z, xv.w};
      float wss[4] = {wv.x, wv.y, wv.z, wv.w};
#pragma unroll
      for (int i = 0; i < 4; i++)
#pragma unroll
        for (int j2 = 0; j2 < 4; j2++) acc[i][j2] += xs[i] * wss[j2];
    }
#pragma unroll
    for (int jj = 0; jj < 4; jj++) {
      float bias = gb1[c0 + jj];
#pragma unroll
      for (int i = 0; i < 4; i++) x2T[c0 + jj][r0 + i] = siluf(acc[i][jj] + bias);
    }
  }
  __syncthreads();
  {  // L3: 16x64 K=256 (linear) + fold w/norm
    int r0 = (t & 3) * 4, c = t >> 2;
    float acc[4] = {};
    for (int k2 = 0; k2 < 256; k2++) {
      float4 xv = *(const float4*)&x2T[k2][r0];
      float wv = gw2[k2 * 64 + c];
      acc[0] += xv.x * wv; acc[1] += xv.y * wv; acc[2] += xv.z * wv; acc[3] += xv.w * wv;
    }
    float snorm = sumw[b];
    float bias = gb2[c];
#pragma unroll
    for (int i = 0; i < 4; i++) {
      int p = p0 + r0 + i;
      float w = scal[(b * PSEL + p) * 8 + 4];
      gg[(b * PSEL + p) * 64 + c] = (acc[i] + bias) * (w / snorm);
    }
  }
}

// fused elem MLP via bf16 MFMA: X1 = silu((W1^T . X0^T)^T), Y = (W2^T . X1^T)^T
// weights as A-operand (pre-swizzled frags in VGPRs), activations as B-operand from LDS.
// D layout: lane holds col m = lane&15, rows n = 4*(lane>>4)+reg -> b64 row-major X1 writes.
#define LP 136  // padded LDS row stride (bf16 elements); 272B = 68 dwords -> bank step 4
__global__ __launch_bounds__(256, 3) void k4_elem(
    const float* __restrict__ pb1, const float* __restrict__ pb2, char* ws) {
  int pc = blockIdx.x, et = blockIdx.y, b = blockIdx.z;
  int t = threadIdx.x;
  int lane = t & 63, w = t >> 6;
  int q = lane >> 4, m4 = lane & 15;
  const float* A0 = (const float*)(ws + WS_A0);
  const float* Ae = (const float*)(ws + WS_AE);
  const float* gg = (const float*)(ws + WS_GG);
  const unsigned short* W1F = (const unsigned short*)(ws + WS_W1F);
  const unsigned short* W2F = (const unsigned short*)(ws + WS_W2F);
  float* agg = (float*)(ws + WS_AGG);
  __shared__ __align__(16) unsigned short x0s[64 * LP];
  __shared__ __align__(16) unsigned short x1s[64 * LP];
  int e0 = et * 8;

  // preload weight fragments (held in VGPRs for the whole block)
  v8s w1f[2][4], w2f[4];
#pragma unroll
  for (int ct = 0; ct < 2; ct++)
#pragma unroll
    for (int kk = 0; kk < 4; kk++)
      w1f[ct][kk] = *(const v8s*)&W1F[(((2 * w + ct) * 4 + kk) * 64 + lane) * 8];
#pragma unroll
  for (int kk = 0; kk < 4; kk++)
    w2f[kk] = *(const v8s*)&W2F[(((w) * 4 + kk) * 64 + lane) * 8];
  // biases for this wave's output columns
  float4 b1v[2];
  b1v[0] = *(const float4*)&pb1[32 * w + 4 * q];
  b1v[1] = *(const float4*)&pb1[32 * w + 16 + 4 * q];
  float4 b2v = *(const float4*)&pb2[16 * w + 4 * q];

  v4f aggR[4];
  const v4f z4 = {0.f, 0.f, 0.f, 0.f};
#pragma unroll
  for (int mt = 0; mt < 4; mt++) aggR[mt] = z4;

  for (int g2 = 0; g2 < 8; g2++) {
    int pbase = pc * 64 + g2 * 8;
    // phase A: X0[m][k] = silu(A0[pbase+(m&7)][k] + Ae[e0+(m>>3)][k]), bf16 into LDS
#pragma unroll
    for (int it = 0; it < 8; it++) {
      int flat = it * 1024 + t * 4;
      int m = flat >> 7, k = flat & 127;
      int pl = m & 7, e = m >> 3;
      float4 a0v = *(const float4*)&A0[(b * PSEL + pbase + pl) * 128 + k];
      float4 aev = *(const float4*)&Ae[(e0 + e) * 128 + k];
      short4 o;
      o.x = (short)f2bf(siluf_fast(a0v.x + aev.x));
      o.y = (short)f2bf(siluf_fast(a0v.y + aev.y));
      o.z = (short)f2bf(siluf_fast(a0v.z + aev.z));
      o.w = (short)f2bf(siluf_fast(a0v.w + aev.w));
      *(short4*)&x0s[m * LP + k] = o;
    }
    __syncthreads();
    // layer1: acc1[mt][ct] (16x16 tiles), A=W1 frags, B=X0 frags
    v4f acc1[4][2];
#pragma unroll
    for (int mt = 0; mt < 4; mt++) { acc1[mt][0] = z4; acc1[mt][1] = z4; }
#pragma unroll
    for (int kk = 0; kk < 4; kk++) {
#pragma unroll
      for (int mt = 0; mt < 4; mt++) {
        v8s bf = *(const v8s*)&x0s[(16 * mt + m4) * LP + 32 * kk + 8 * q];
        acc1[mt][0] = __builtin_amdgcn_mfma_f32_16x16x32_bf16(w1f[0][kk], bf, acc1[mt][0], 0, 0, 0);
        acc1[mt][1] = __builtin_amdgcn_mfma_f32_16x16x32_bf16(w1f[1][kk], bf, acc1[mt][1], 0, 0, 0);
      }
    }
    // epilogue: silu + bf16, write X1[m][n] (lane holds 4 consecutive n per tile)
#pragma unroll
    for (int mt = 0; mt < 4; mt++) {
#pragma unroll
      for (int ct = 0; ct < 2; ct++) {
        float4 bias = b1v[ct];
        short4 o;
        o.x = (short)f2bf(siluf_fast(acc1[mt][ct][0] + bias.x));
        o.y = (short)f2bf(siluf_fast(acc1[mt][ct][1] + bias.y));
        o.z = (short)f2bf(siluf_fast(acc1[mt][ct][2] + bias.z));
        o.w = (short)f2bf(siluf_fast(acc1[mt][ct][3] + bias.w));
        int n0 = 32 * w + 16 * ct + 4 * q;
        *(short4*)&x1s[(16 * mt + m4) * LP + n0] = o;
      }
    }
    __syncthreads();
    // layer2: acc2[mt], A=W2 frags, B=X1 frags
    v4f acc2[4];
#pragma unroll
    for (int mt = 0; mt < 4; mt++) acc2[mt] = z4;
#pragma unroll
    for (int kk = 0; kk < 4; kk++) {
#pragma unroll
      for (int mt = 0; mt < 4; mt++) {
        v8s bf = *(const v8s*)&x1s[(16 * mt + m4) * LP + 32 * kk + 8 * q];
        acc2[mt] = __builtin_amdgcn_mfma_f32_16x16x32_bf16(w2f[kk], bf, acc2[mt], 0, 0, 0);
      }
    }
    // aggregation: lane has fixed pl = lane&7; gg row independent of mt
    float4 gv = *(const float4*)&gg[(b * PSEL + pbase + (lane & 7)) * 64 + 16 * w + 4 * q];
#pragma unroll
    for (int mt = 0; mt < 4; mt++) {
      aggR[mt][0] += gv.x * (acc2[mt][0] + b2v.x);
      aggR[mt][1] += gv.y * (acc2[mt][1] + b2v.y);
      aggR[mt][2] += gv.z * (acc2[mt][2] + b2v.z);
      aggR[mt][3] += gv.w * (acc2[mt][3] + b2v.w);
    }
  }
  // reduce over pl (lanes differing in bits 0..2), then atomicAdd
#pragma unroll
  for (int mt = 0; mt < 4; mt++) {
#pragma unroll
    for (int r = 0; r < 4; r++) {
      float v = aggR[mt][r];
      v += __shfl_xor(v, 1);
      v += __shfl_xor(v, 2);
      v += __shfl_xor(v, 4);
      if ((lane & 7) == 0) {
        int e = 2 * mt + ((lane >> 3) & 1);
        int n = 16 * w + 4 * q + r;
        atomicAdd(&agg[(b * NEL + e0 + e) * 64 + n], v);
      }
    }
  }
}

// output MLP 64->256 silu ->128
__global__ __launch_bounds__(256) void k5_out(
    const float* __restrict__ ow0, const float* __restrict__ ob0,
    const float* __restrict__ ow1, const float* __restrict__ ob1,
    const char* ws, float* __restrict__ out) {
  int row0 = blockIdx.x * 16;  // rows over (b*128+e), 2048 total
  int t = threadIdx.x;
  const float* agg = (const float*)(ws + WS_AGG);
  __shared__ float xT[64][16];
  __shared__ float x1T[256][16];
  {
    int row = t & 15, fs = t >> 4;
    for (int f = fs; f < 64; f += 16) xT[f][row] = agg[(row0 + row) * 64 + f];
  }
  __syncthreads();
  {  // L1: 16x256 K=64
    int r0 = (t & 3) * 4, c0 = (t >> 2) * 4;
    float acc[4][4] = {};
    for (int k2 = 0; k2 < 64; k2++) {
      float4 xv = *(const float4*)&xT[k2][r0];
      float4 wv = *(const float4*)&ow0[k2 * 256 + c0];
      float xs[4] = {xv.x, xv.y, xv.z, xv.w};
      float wss[4] = {wv.x, wv.y, wv.z, wv.w};
#pragma unroll
      for (int i = 0; i < 4; i++)
#pragma unroll
        for (int j2 = 0; j2 < 4; j2++) acc[i][j2] += xs[i] * wss[j2];
    }
#pragma unroll
    for (int jj = 0; jj < 4; jj++) {
      float bias = ob0[c0 + jj];
#pragma unroll
      for (int i = 0; i < 4; i++) x1T[c0 + jj][r0 + i] = siluf(acc[i][jj] + bias);
    }
  }
  __syncthreads();
  {  // L2: 16x128 K=256 (linear), write out
    int r0 = (t & 3) * 4, c0 = (t >> 2) * 2;
    float acc[4][2] = {};
    for (int k2 = 0; k2 < 256; k2++) {
      float4 xv = *(const float4*)&x1T[k2][r0];
      float2 wv = *(const float2*)&ow1[k2 * 128 + c0];
      float xs[4] = {xv.x, xv.y, xv.z, xv.w};
#pragma unroll
      for (int i = 0; i < 4; i++) {
        acc[i][0] += xs[i] * wv.x;
        acc[i][1] += xs[i] * wv.y;
      }
    }
#pragma unroll
    for (int i = 0; i < 4; i++)
#pragma unroll
      for (int j2 = 0; j2 < 2; j2++)
        out[(row0 + r0 + i) * 128 + c0 + j2] = acc[i][j2] + ob1[c0 + j2];
  }
}

extern "C" void kernel_launch(void* const* d_in, const int* in_sizes, int n_in,
                              void* d_out, int out_size, void* d_ws, size_t ws_size,
                              hipStream_t stream) {
  const float* h     = (const float*)d_in[0];
  const int*   z     = (const int*)d_in[1];
  const float* pos   = (const float*)d_in[2];
  const float* efeat = (const float*)d_in[4];
  const float* zemb  = (const float*)d_in[5];
  const float* pw0 = (const float*)d_in[6];
  const float* pb0 = (const float*)d_in[7];
  const float* pw1 = (const float*)d_in[8];
  const float* pb1 = (const float*)d_in[9];
  const float* pw2 = (const float*)d_in[10];
  const float* pb2 = (const float*)d_in[11];
  const float* gw0 = (const float*)d_in[12];
  const float* gb0 = (const float*)d_in[13];
  const float* gw1 = (const float*)d_in[14];
  const float* gb1 = (const float*)d_in[15];
  const float* gw2 = (const float*)d_in[16];
  const float* gb2 = (const float*)d_in[17];
  const float* ow0 = (const float*)d_in[18];
  const float* ob0 = (const float*)d_in[19];
  const float* ow1 = (const float*)d_in[20];
  const float* ob1 = (const float*)d_in[21];
  char* ws = (char*)d_ws;
  float* out = (float*)d_out;

  hipMemsetAsync(ws + WS_AGG, 0, NB * NEL * 64 * sizeof(float), stream);
  k0_flag<<<1, 64, 0, stream>>>(z, (int*)(ws + WS_FLAG));
  k1_select<<<16, 256, 0, stream>>>(pos, ws);
  k2a_ae<<<128, 128, 0, stream>>>(efeat, pw0, ws);
  k2c_wfrag<<<96, 256, 0, stream>>>(pw1, pw2, ws);
  k2b_a0<<<dim3(256, 16), 128, 0, stream>>>(z, zemb, pw0, pb0, ws);
  k3_geom<<<256, 256, 0, stream>>>(h, gw0, gb0, gw1, gb1, gw2, gb2, ws);
  k4_elem<<<dim3(4, 16, 16), 256, 0, stream>>>(pb1, pb2, ws);
  k5_out<<<128, 256, 0, stream>>>(ow0, ob0, ow1, ob1, ws, out);
}

// Round 3
// 279.662 us; speedup vs baseline: 2.6154x; 1.3851x over previous
//
#include <hip/hip_runtime.h>
#include <math.h>

#define NB 16
#define NA 64
#define NHD 128
#define NPAIR 2016
#define PSEL 256
#define NEL 128
// ws byte offsets (all 256-aligned)
#define WS_FLAG   0
#define WS_SUMW   1024
#define WS_SELJ   2048
#define WS_SELK   (WS_SELJ + 16384)
#define WS_SCAL   (WS_SELK + 16384)      // [4096][8] f32
#define WS_AE     (WS_SCAL + 131072)     // [128][128] f32
#define WS_GG     (WS_AE + 65536)        // [4096][64] f32
#define WS_A0     (WS_GG + 1048576)      // [4096][128] f32
#define WS_AGG    (WS_A0 + 2097152)      // [16][128][64] f32
#define WS_W1F    (WS_AGG + 524288)      // bf16 frag pw1, 32KB
#define WS_W2F    (WS_W1F + 32768)       // bf16 frag pw2, 16KB
#define WS_G0F    (WS_W2F + 16384)       // bf16 frag gw0 (K padded 384), 192KB
#define WS_G1F    (WS_G0F + 196608)      // bf16 frag gw1, 128KB
#define WS_G2F    (WS_G1F + 131072)      // bf16 frag gw2, 32KB

typedef short v8s __attribute__((ext_vector_type(8)));
typedef float v4f __attribute__((ext_vector_type(4)));

__device__ __forceinline__ float siluf_fast(float x) {
  float e = __expf(-x);
  return x * __builtin_amdgcn_rcpf(1.0f + e);  // v_rcp_f32: ~1ulp, 5 VALU vs ~15 for IEEE div
}
__device__ __forceinline__ unsigned short f2bf(float f) {
  unsigned int u = __float_as_uint(f);
  return (unsigned short)((u + 0x7fffu + ((u >> 16) & 1u)) >> 16);
}
__device__ __forceinline__ float cutf(float r) {
  return (r <= 6.0f) ? (0.5f * (cosf((3.14159265358979323846f * r) / 6.0f) + 1.0f)) : 0.0f;
}
__device__ __forceinline__ float rbff(float r, int i) {
  float rc = fminf(r, 6.0f);
  float c = (float)i * (6.0f / 31.0f);
  float d = rc - c;
  return expf(-26.694445f * d * d);
}
__device__ __forceinline__ void pair_jk(int p, int& j, int& k) {
  int jj = (int)((127.0 - sqrt(16129.0 - 8.0 * (double)p)) * 0.5);
  if (jj < 0) jj = 0;
  if (jj > 62) jj = 62;
  while (jj < 62 && (63 * (jj + 1) - ((jj + 1) * jj) / 2) <= p) jj++;
  while (jj > 0 && (63 * jj - (jj * (jj - 1)) / 2) > p) jj--;
  j = jj;
  k = p - (63 * jj - (jj * (jj - 1)) / 2) + jj + 1;
}

// ---- prep: z-width flag + Ae + all bf16 weight fragments (A-operand order: A[n][k])
// frag idx: [((nt*NKK + kk)*64 + lane)*8 + j] -> n = 16nt+(lane&15), k = 32kk+(lane>>4)*8+j
__global__ __launch_bounds__(256) void k_prep(
    const int* __restrict__ z, const float* __restrict__ ef,
    const float* __restrict__ pw0, const float* __restrict__ pw1,
    const float* __restrict__ pw2, const float* __restrict__ gw0,
    const float* __restrict__ gw1, const float* __restrict__ gw2, char* ws) {
  int idx = blockIdx.x * 256 + threadIdx.x;  // 0..221183
  if (idx == 0) *((int*)(ws + WS_FLAG)) = (z[1] == 0) ? 1 : 0;
  if (idx < 16384) {  // W1F: 128x128, NKK=4
    int j = idx & 7, l = (idx >> 3) & 63, t2 = idx >> 9;
    int kk = t2 & 3, nt = t2 >> 2;
    int n = 16 * nt + (l & 15), k = 32 * kk + (l >> 4) * 8 + j;
    ((unsigned short*)(ws + WS_W1F))[idx] = f2bf(pw1[k * 128 + n]);
  } else if (idx < 24576) {  // W2F: 128x64, NKK=4
    int id = idx - 16384;
    int j = id & 7, l = (id >> 3) & 63, t2 = id >> 9;
    int kk = t2 & 3, nt = t2 >> 2;
    int n = 16 * nt + (l & 15), k = 32 * kk + (l >> 4) * 8 + j;
    ((unsigned short*)(ws + WS_W2F))[id] = f2bf(pw2[k * 64 + n]);
  } else if (idx < 122880) {  // G0F: 353(->384)x256, NKK=12
    int id = idx - 24576;
    int j = id & 7, l = (id >> 3) & 63, t2 = id >> 9;  // 0..191
    int kk = t2 % 12, nt = t2 / 12;
    int n = 16 * nt + (l & 15), k = 32 * kk + (l >> 4) * 8 + j;
    float v = (k < 353) ? gw0[k * 256 + n] : 0.0f;
    ((unsigned short*)(ws + WS_G0F))[id] = f2bf(v);
  } else if (idx < 188416) {  // G1F: 256x256, NKK=8
    int id = idx - 122880;
    int j = id & 7, l = (id >> 3) & 63, t2 = id >> 9;  // 0..127
    int kk = t2 & 7, nt = t2 >> 3;
    int n = 16 * nt + (l & 15), k = 32 * kk + (l >> 4) * 8 + j;
    ((unsigned short*)(ws + WS_G1F))[id] = f2bf(gw1[k * 256 + n]);
  } else if (idx < 204800) {  // G2F: 256x64, NKK=8
    int id = idx - 188416;
    int j = id & 7, l = (id >> 3) & 63, t2 = id >> 9;  // 0..31
    int kk = t2 & 7, nt = t2 >> 3;
    int n = 16 * nt + (l & 15), k = 32 * kk + (l >> 4) * 8 + j;
    ((unsigned short*)(ws + WS_G2F))[id] = f2bf(gw2[k * 64 + n]);
  } else if (idx < 221184) {  // Ae[e][d] = e_feat[e] @ pw0[64:96]
    int id = idx - 204800;
    int e = id >> 7, d = id & 127;
    float a = 0.0f;
    for (int i = 0; i < 32; i++) a += ef[e * 32 + i] * pw0[(64 + i) * 128 + d];
    ((float*)(ws + WS_AE))[e * 128 + d] = a;
  }
}

// per-batch pair scoring + exact stable top-256 via bitonic sort of (score|idx) keys
__global__ __launch_bounds__(256) void k1_select(const float* __restrict__ pos, char* ws) {
#pragma clang fp contract(off)
  int b = blockIdx.x, t = threadIdx.x;
  __shared__ float px[64], py[64], pz[64], rr[64];
  __shared__ unsigned long long keys[2048];
  __shared__ float wred[256];
  if (t < 64) {
    px[t] = pos[(b * 64 + t) * 3 + 0];
    py[t] = pos[(b * 64 + t) * 3 + 1];
    pz[t] = pos[(b * 64 + t) * 3 + 2];
  }
  __syncthreads();
  if (t < 64) {
    float dx = px[t] - px[0], dy = py[t] - py[0], dz = pz[t] - pz[0];
    rr[t] = sqrtf((dx * dx + dy * dy) + dz * dz);
  }
  __syncthreads();
  for (int p = t; p < 2048; p += 256) {
    unsigned long long key = 0xFFFFFFFFFFFFFFFFull;
    if (p < NPAIR) {
      int j, k;
      pair_jk(p, j, k);
      bool vj = (j != 0) && (rr[j] <= 6.0f);
      bool vk = (rr[k] <= 6.0f);
      unsigned int sb = 0x7f800000u;  // +inf
      if (vj && vk) {
        float dx = px[k] - px[j], dy = py[k] - py[j], dz = pz[k] - pz[j];
        float rjk = sqrtf((dx * dx + dy * dy) + dz * dz);
        float score = (rr[j] + rr[k]) + 0.5f * rjk;
        sb = __float_as_uint(score);
      }
      key = (((unsigned long long)sb) << 32) | (unsigned int)p;
    }
    keys[p] = key;
  }
  __syncthreads();
  for (int kk = 2; kk <= 2048; kk <<= 1) {
    for (int jj = kk >> 1; jj > 0; jj >>= 1) {
      for (int i = t; i < 2048; i += 256) {
        int ixj = i ^ jj;
        if (ixj > i) {
          unsigned long long a = keys[i], c = keys[ixj];
          bool up = ((i & kk) == 0);
          bool sw = up ? (a > c) : (a < c);
          if (sw) { keys[i] = c; keys[ixj] = a; }
        }
      }
      __syncthreads();
    }
  }
  float myw = 0.0f;
  if (t < PSEL) {
    unsigned long long key = keys[t];
    unsigned int sb = (unsigned int)(key >> 32);
    int p = (int)(key & 0xFFFFFFFFu);
    bool pv = (sb < 0x7f800000u);
    int j = 0, k = 0;
    if (pv) pair_jk(p, j, k);
    float r0j = rr[j], r0k = rr[k];
    float vjx = px[j] - px[0], vjy = py[j] - py[0], vjz = pz[j] - pz[0];
    float vkx = px[k] - px[0], vky = py[k] - py[0], vkz = pz[k] - pz[0];
    float dx = px[k] - px[j], dy = py[k] - py[j], dz = pz[k] - pz[j];
    float rjk = sqrtf((dx * dx + dy * dy) + dz * dz);
    float ij = 1.0f / fmaxf(r0j, 1e-8f);
    float ik = 1.0f / fmaxf(r0k, 1e-8f);
    float cs = (vjx * vkx + vjy * vky + vjz * vkz) * ij * ik;
    cs = fminf(1.0f, fmaxf(-1.0f, cs));
    float w = pv ? (cutf(r0j) * cutf(r0k) * cutf(rjk)) : 0.0f;
    int* selJ = (int*)(ws + WS_SELJ);
    int* selK = (int*)(ws + WS_SELK);
    float* scal = (float*)(ws + WS_SCAL);
    selJ[b * PSEL + t] = j;
    selK[b * PSEL + t] = k;
    float* s = &scal[(b * PSEL + t) * 8];
    s[0] = r0j; s[1] = r0k; s[2] = rjk; s[3] = cs; s[4] = w;
    myw = w;
  }
  wred[t] = myw;
  __syncthreads();
  for (int s2 = 128; s2 > 0; s2 >>= 1) {
    if (t < s2) wred[t] += wred[t + s2];
    __syncthreads();
  }
  if (t == 0) ((float*)(ws + WS_SUMW))[b] = fmaxf(wred[0], 1e-8f);
}

// A0[b,p][d] = z_emb[zj]@pw0[0:32] + z_emb[zk]@pw0[32:64] + pb0
__global__ __launch_bounds__(128) void k2b_a0(const int* __restrict__ z,
                                              const float* __restrict__ zemb,
                                              const float* __restrict__ pw0,
                                              const float* __restrict__ pb0, char* ws) {
  int p = blockIdx.x, b = blockIdx.y, d = threadIdx.x;
  const int* selJ = (const int*)(ws + WS_SELJ);
  const int* selK = (const int*)(ws + WS_SELK);
  int is64 = *((const int*)(ws + WS_FLAG));
  float* A0 = (float*)(ws + WS_A0);
  int j = selJ[b * PSEL + p], k = selK[b * PSEL + p];
  __shared__ float zr[64];
  if (d < 64) {
    int atom = (d < 32) ? j : k;
    int zi = b * 64 + atom;
    int zv = is64 ? z[zi * 2] : z[zi];
    zr[d] = zemb[zv * 32 + (d & 31)];
  }
  __syncthreads();
  float a = pb0[d];
  for (int i = 0; i < 32; i++) {
    a += zr[i] * pw0[i * 128 + d];
    a += zr[32 + i] * pw0[(32 + i) * 128 + d];
  }
  A0[(b * PSEL + p) * 128 + d] = a;
}

// geom MLP via bf16 MFMA: 353(pad384)->256->256->64, folds w/sumw into gg
// 16 rows(pairs)/block, 4 waves x 64 cols; weight frags streamed from global
#define LP3 392  // xs row stride (bf16): 196 dw, /4=49 odd -> uniform b128 bank spread
#define LQ3 264  // x1s/x2s row stride: 132 dw, /4=33 odd
__global__ __launch_bounds__(256) void k3_geom(const float* __restrict__ h,
    const float* __restrict__ gb0, const float* __restrict__ gb1,
    const float* __restrict__ gb2, char* ws) {
  int blk = blockIdx.x;
  int b = blk >> 4, p0 = (blk & 15) * 16;
  int t = threadIdx.x;
  int lane = t & 63, w = t >> 6;
  int q = lane >> 4, m4 = lane & 15;
  const int* selJ = (const int*)(ws + WS_SELJ);
  const int* selK = (const int*)(ws + WS_SELK);
  const float* scal = (const float*)(ws + WS_SCAL);
  const float* sumw = (const float*)(ws + WS_SUMW);
  float* gg = (float*)(ws + WS_GG);
  const unsigned short* G0F = (const unsigned short*)(ws + WS_G0F);
  const unsigned short* G1F = (const unsigned short*)(ws + WS_G1F);
  const unsigned short* G2F = (const unsigned short*)(ws + WS_G2F);
  __shared__ __align__(16) unsigned short xs[16 * LP3];
  __shared__ __align__(16) unsigned short x1s[16 * LQ3];
  __shared__ __align__(16) unsigned short x2s[16 * LQ3];
  const v4f z4 = {0.f, 0.f, 0.f, 0.f};
  {  // stage X[row][f], f in [0,384)
    int row = t & 15, fs = t >> 4;
    int p = p0 + row;
    int j = selJ[b * PSEL + p], k = selK[b * PSEL + p];
    const float* s = &scal[(b * PSEL + p) * 8];
    float r0j = s[0], r0k = s[1], rjk = s[2], cs = s[3];
    for (int f = fs; f < 384; f += 16) {
      float v;
      if (f < 128) v = h[(b * 64 + j) * 128 + f];
      else if (f < 256) v = h[(b * 64 + k) * 128 + (f - 128)];
      else if (f < 288) v = rbff(r0j, f - 256);
      else if (f < 320) v = rbff(r0k, f - 288);
      else if (f < 352) v = rbff(rjk, f - 320);
      else if (f == 352) v = cs;
      else v = 0.0f;
      xs[row * LP3 + f] = f2bf(v);
    }
  }
  __syncthreads();
  {  // L1: out 16 x 256 (wave w: cols 64w..64w+63), K=384
    v4f acc[4];
#pragma unroll
    for (int nt = 0; nt < 4; nt++) acc[nt] = z4;
    for (int kk = 0; kk < 12; kk++) {
      v8s bf = *(const v8s*)&xs[m4 * LP3 + 32 * kk + 8 * q];
#pragma unroll
      for (int nt = 0; nt < 4; nt++) {
        v8s wf = *(const v8s*)&G0F[(((4 * w + nt) * 12 + kk) * 64 + lane) * 8];
        acc[nt] = __builtin_amdgcn_mfma_f32_16x16x32_bf16(wf, bf, acc[nt], 0, 0, 0);
      }
    }
#pragma unroll
    for (int nt = 0; nt < 4; nt++) {
      int n0 = 64 * w + 16 * nt + 4 * q;
      float4 bias = *(const float4*)&gb0[n0];
      short4 o;
      o.x = (short)f2bf(siluf_fast(acc[nt][0] + bias.x));
      o.y = (short)f2bf(siluf_fast(acc[nt][1] + bias.y));
      o.z = (short)f2bf(siluf_fast(acc[nt][2] + bias.z));
      o.w = (short)f2bf(siluf_fast(acc[nt][3] + bias.w));
      *(short4*)&x1s[m4 * LQ3 + n0] = o;
    }
  }
  __syncthreads();
  {  // L2: out 16 x 256, K=256
    v4f acc[4];
#pragma unroll
    for (int nt = 0; nt < 4; nt++) acc[nt] = z4;
    for (int kk = 0; kk < 8; kk++) {
      v8s bf = *(const v8s*)&x1s[m4 * LQ3 + 32 * kk + 8 * q];
#pragma unroll
      for (int nt = 0; nt < 4; nt++) {
        v8s wf = *(const v8s*)&G1F[(((4 * w + nt) * 8 + kk) * 64 + lane) * 8];
        acc[nt] = __builtin_amdgcn_mfma_f32_16x16x32_bf16(wf, bf, acc[nt], 0, 0, 0);
      }
    }
#pragma unroll
    for (int nt = 0; nt < 4; nt++) {
      int n0 = 64 * w + 16 * nt + 4 * q;
      float4 bias = *(const float4*)&gb1[n0];
      short4 o;
      o.x = (short)f2bf(siluf_fast(acc[nt][0] + bias.x));
      o.y = (short)f2bf(siluf_fast(acc[nt][1] + bias.y));
      o.z = (short)f2bf(siluf_fast(acc[nt][2] + bias.z));
      o.w = (short)f2bf(siluf_fast(acc[nt][3] + bias.w));
      *(short4*)&x2s[m4 * LQ3 + n0] = o;
    }
  }
  __syncthreads();
  {  // L3: out 16 x 64 (wave w: cols 16w..16w+15), K=256, linear + fold w/norm
    v4f acc = z4;
    for (int kk = 0; kk < 8; kk++) {
      v8s bf = *(const v8s*)&x2s[m4 * LQ3 + 32 * kk + 8 * q];
      v8s wf = *(const v8s*)&G2F[((w * 8 + kk) * 64 + lane) * 8];
      acc = __builtin_amdgcn_mfma_f32_16x16x32_bf16(wf, bf, acc, 0, 0, 0);
    }
    int p = p0 + m4;
    float wp = scal[(b * PSEL + p) * 8 + 4];
    float sc = wp * __builtin_amdgcn_rcpf(sumw[b]);
    // sumw >= 1e-8 guaranteed; rcp approx fine (folded scale)
    float s2 = wp / sumw[b];
    (void)sc;
    int n0 = 16 * w + 4 * q;
    float4 bias = *(const float4*)&gb2[n0];
    float4 o;
    o.x = (acc[0] + bias.x) * s2;
    o.y = (acc[1] + bias.y) * s2;
    o.z = (acc[2] + bias.z) * s2;
    o.w = (acc[3] + bias.w) * s2;
    *(float4*)&gg[(b * PSEL + p) * 64 + n0] = o;
  }
}

// fused elem MLP via bf16 MFMA: X1 = silu((W1^T . X0^T)^T), Y = (W2^T . X1^T)^T
#define LP 136  // padded LDS row stride (bf16); 68 dw, /4=17 odd -> uniform bank spread
__global__ __launch_bounds__(256, 3) void k4_elem(
    const float* __restrict__ pb1, const float* __restrict__ pb2, char* ws) {
  int pc = blockIdx.x, et = blockIdx.y, b = blockIdx.z;
  int t = threadIdx.x;
  int lane = t & 63, w = t >> 6;
  int q = lane >> 4, m4 = lane & 15;
  const float* A0 = (const float*)(ws + WS_A0);
  const float* Ae = (const float*)(ws + WS_AE);
  const float* gg = (const float*)(ws + WS_GG);
  const unsigned short* W1F = (const unsigned short*)(ws + WS_W1F);
  const unsigned short* W2F = (const unsigned short*)(ws + WS_W2F);
  float* agg = (float*)(ws + WS_AGG);
  __shared__ __align__(16) unsigned short x0s[64 * LP];
  __shared__ __align__(16) unsigned short x1s[64 * LP];
  int e0 = et * 8;

  v8s w1f[2][4], w2f[4];
#pragma unroll
  for (int ct = 0; ct < 2; ct++)
#pragma unroll
    for (int kk = 0; kk < 4; kk++)
      w1f[ct][kk] = *(const v8s*)&W1F[(((2 * w + ct) * 4 + kk) * 64 + lane) * 8];
#pragma unroll
  for (int kk = 0; kk < 4; kk++)
    w2f[kk] = *(const v8s*)&W2F[(((w) * 4 + kk) * 64 + lane) * 8];
  float4 b1v[2];
  b1v[0] = *(const float4*)&pb1[32 * w + 4 * q];
  b1v[1] = *(const float4*)&pb1[32 * w + 16 + 4 * q];
  float4 b2v = *(const float4*)&pb2[16 * w + 4 * q];

  v4f aggR[4];
  const v4f z4 = {0.f, 0.f, 0.f, 0.f};
#pragma unroll
  for (int mt = 0; mt < 4; mt++) aggR[mt] = z4;

  for (int g2 = 0; g2 < 8; g2++) {
    int pbase = pc * 64 + g2 * 8;
#pragma unroll
    for (int it = 0; it < 8; it++) {
      int flat = it * 1024 + t * 4;
      int m = flat >> 7, k = flat & 127;
      int pl = m & 7, e = m >> 3;
      float4 a0v = *(const float4*)&A0[(b * PSEL + pbase + pl) * 128 + k];
      float4 aev = *(const float4*)&Ae[(e0 + e) * 128 + k];
      short4 o;
      o.x = (short)f2bf(siluf_fast(a0v.x + aev.x));
      o.y = (short)f2bf(siluf_fast(a0v.y + aev.y));
      o.z = (short)f2bf(siluf_fast(a0v.z + aev.z));
      o.w = (short)f2bf(siluf_fast(a0v.w + aev.w));
      *(short4*)&x0s[m * LP + k] = o;
    }
    __syncthreads();
    v4f acc1[4][2];
#pragma unroll
    for (int mt = 0; mt < 4; mt++) { acc1[mt][0] = z4; acc1[mt][1] = z4; }
#pragma unroll
    for (int kk = 0; kk < 4; kk++) {
#pragma unroll
      for (int mt = 0; mt < 4; mt++) {
        v8s bf = *(const v8s*)&x0s[(16 * mt + m4) * LP + 32 * kk + 8 * q];
        acc1[mt][0] = __builtin_amdgcn_mfma_f32_16x16x32_bf16(w1f[0][kk], bf, acc1[mt][0], 0, 0, 0);
        acc1[mt][1] = __builtin_amdgcn_mfma_f32_16x16x32_bf16(w1f[1][kk], bf, acc1[mt][1], 0, 0, 0);
      }
    }
#pragma unroll
    for (int mt = 0; mt < 4; mt++) {
#pragma unroll
      for (int ct = 0; ct < 2; ct++) {
        float4 bias = b1v[ct];
        short4 o;
        o.x = (short)f2bf(siluf_fast(acc1[mt][ct][0] + bias.x));
        o.y = (short)f2bf(siluf_fast(acc1[mt][ct][1] + bias.y));
        o.z = (short)f2bf(siluf_fast(acc1[mt][ct][2] + bias.z));
        o.w = (short)f2bf(siluf_fast(acc1[mt][ct][3] + bias.w));
        int n0 = 32 * w + 16 * ct + 4 * q;
        *(short4*)&x1s[(16 * mt + m4) * LP + n0] = o;
      }
    }
    __syncthreads();
    v4f acc2[4];
#pragma unroll
    for (int mt = 0; mt < 4; mt++) acc2[mt] = z4;
#pragma unroll
    for (int kk = 0; kk < 4; kk++) {
#pragma unroll
      for (int mt = 0; mt < 4; mt++) {
        v8s bf = *(const v8s*)&x1s[(16 * mt + m4) * LP + 32 * kk + 8 * q];
        acc2[mt] = __builtin_amdgcn_mfma_f32_16x16x32_bf16(w2f[kk], bf, acc2[mt], 0, 0, 0);
      }
    }
    float4 gv = *(const float4*)&gg[(b * PSEL + pbase + (lane & 7)) * 64 + 16 * w + 4 * q];
#pragma unroll
    for (int mt = 0; mt < 4; mt++) {
      aggR[mt][0] += gv.x * (acc2[mt][0] + b2v.x);
      aggR[mt][1] += gv.y * (acc2[mt][1] + b2v.y);
      aggR[mt][2] += gv.z * (acc2[mt][2] + b2v.z);
      aggR[mt][3] += gv.w * (acc2[mt][3] + b2v.w);
    }
  }
#pragma unroll
  for (int mt = 0; mt < 4; mt++) {
#pragma unroll
    for (int r = 0; r < 4; r++) {
      float v = aggR[mt][r];
      v += __shfl_xor(v, 1);
      v += __shfl_xor(v, 2);
      v += __shfl_xor(v, 4);
      if ((lane & 7) == 0) {
        int e = 2 * mt + ((lane >> 3) & 1);
        int n = 16 * w + 4 * q + r;
        atomicAdd(&agg[(b * NEL + e0 + e) * 64 + n], v);
      }
    }
  }
}

// output MLP 64->256 silu ->128 (f32 vector; small)
__global__ __launch_bounds__(256) void k5_out(
    const float* __restrict__ ow0, const float* __restrict__ ob0,
    const float* __restrict__ ow1, const float* __restrict__ ob1,
    const char* ws, float* __restrict__ out) {
  int row0 = blockIdx.x * 16;
  int t = threadIdx.x;
  const float* agg = (const float*)(ws + WS_AGG);
  __shared__ float xT[64][16];
  __shared__ float x1T[256][16];
  {
    int row = t & 15, fs = t >> 4;
    for (int f = fs; f < 64; f += 16) xT[f][row] = agg[(row0 + row) * 64 + f];
  }
  __syncthreads();
  {
    int r0 = (t & 3) * 4, c0 = (t >> 2) * 4;
    float acc[4][4] = {};
    for (int k2 = 0; k2 < 64; k2++) {
      float4 xv = *(const float4*)&xT[k2][r0];
      float4 wv = *(const float4*)&ow0[k2 * 256 + c0];
      float xs2[4] = {xv.x, xv.y, xv.z, xv.w};
      float wss[4] = {wv.x, wv.y, wv.z, wv.w};
#pragma unroll
      for (int i = 0; i < 4; i++)
#pragma unroll
        for (int j2 = 0; j2 < 4; j2++) acc[i][j2] += xs2[i] * wss[j2];
    }
#pragma unroll
    for (int jj = 0; jj < 4; jj++) {
      float bias = ob0[c0 + jj];
#pragma unroll
      for (int i = 0; i < 4; i++) x1T[c0 + jj][r0 + i] = siluf_fast(acc[i][jj] + bias);
    }
  }
  __syncthreads();
  {
    int r0 = (t & 3) * 4, c0 = (t >> 2) * 2;
    float acc[4][2] = {};
    for (int k2 = 0; k2 < 256; k2++) {
      float4 xv = *(const float4*)&x1T[k2][r0];
      float2 wv = *(const float2*)&ow1[k2 * 128 + c0];
      float xs2[4] = {xv.x, xv.y, xv.z, xv.w};
#pragma unroll
      for (int i = 0; i < 4; i++) {
        acc[i][0] += xs2[i] * wv.x;
        acc[i][1] += xs2[i] * wv.y;
      }
    }
#pragma unroll
    for (int i = 0; i < 4; i++)
#pragma unroll
      for (int j2 = 0; j2 < 2; j2++)
        out[(row0 + r0 + i) * 128 + c0 + j2] = acc[i][j2] + ob1[c0 + j2];
  }
}

extern "C" void kernel_launch(void* const* d_in, const int* in_sizes, int n_in,
                              void* d_out, int out_size, void* d_ws, size_t ws_size,
                              hipStream_t stream) {
  const float* h     = (const float*)d_in[0];
  const int*   z     = (const int*)d_in[1];
  const float* pos   = (const float*)d_in[2];
  const float* efeat = (const float*)d_in[4];
  const float* zemb  = (const float*)d_in[5];
  const float* pw0 = (const float*)d_in[6];
  const float* pb0 = (const float*)d_in[7];
  const float* pw1 = (const float*)d_in[8];
  const float* pb1 = (const float*)d_in[9];
  const float* pw2 = (const float*)d_in[10];
  const float* pb2 = (const float*)d_in[11];
  const float* gw0 = (const float*)d_in[12];
  const float* gb0 = (const float*)d_in[13];
  const float* gw1 = (const float*)d_in[14];
  const float* gb1 = (const float*)d_in[15];
  const float* gw2 = (const float*)d_in[16];
  const float* gb2 = (const float*)d_in[17];
  const float* ow0 = (const float*)d_in[18];
  const float* ob0 = (const float*)d_in[19];
  const float* ow1 = (const float*)d_in[20];
  const float* ob1 = (const float*)d_in[21];
  char* ws = (char*)d_ws;
  float* out = (float*)d_out;

  hipMemsetAsync(ws + WS_AGG, 0, NB * NEL * 64 * sizeof(float), stream);
  k_prep<<<864, 256, 0, stream>>>(z, efeat, pw0, pw1, pw2, gw0, gw1, gw2, ws);
  k1_select<<<16, 256, 0, stream>>>(pos, ws);
  k2b_a0<<<dim3(256, 16), 128, 0, stream>>>(z, zemb, pw0, pb0, ws);
  k3_geom<<<256, 256, 0, stream>>>(h, gb0, gb1, gb2, ws);
  k4_elem<<<dim3(4, 16, 16), 256, 0, stream>>>(pb1, pb2, ws);
  k5_out<<<128, 256, 0, stream>>>(ow0, ob0, ow1, ob1, ws, out);
}

// Round 4
// 252.912 us; speedup vs baseline: 2.8920x; 1.1058x over previous
//
#include <hip/hip_runtime.h>
#include <math.h>

#define NB 16
#define NA 64
#define NHD 128
#define NPAIR 2016
#define PSEL 256
#define NEL 128
// ws byte offsets (all 256-aligned)
#define WS_FLAG   0
#define WS_SUMW   1024
#define WS_SELJ   2048
#define WS_SELK   (WS_SELJ + 16384)
#define WS_SCAL   (WS_SELK + 16384)      // [4096][8] f32
#define WS_AE     (WS_SCAL + 131072)     // [128][128] f32
#define WS_GG     (WS_AE + 65536)        // [4096][64] f32
#define WS_A0     (WS_GG + 1048576)      // [4096][128] f32
#define WS_AGG    (WS_A0 + 2097152)      // [16][128][64] f32
#define WS_W1F    (WS_AGG + 524288)      // bf16 frag pw1, 32KB
#define WS_W2F    (WS_W1F + 32768)       // bf16 frag pw2, 16KB
#define WS_G0F    (WS_W2F + 16384)       // bf16 frag gw0 (K padded 384), 192KB
#define WS_G1F    (WS_G0F + 196608)      // bf16 frag gw1, 128KB
#define WS_G2F    (WS_G1F + 131072)      // bf16 frag gw2, 32KB

typedef short v8s __attribute__((ext_vector_type(8)));
typedef float v4f __attribute__((ext_vector_type(4)));

__device__ __forceinline__ float siluf_fast(float x) {
  float e = __expf(-x);
  return x * __builtin_amdgcn_rcpf(1.0f + e);  // v_rcp_f32: ~1ulp, 5 VALU vs ~15 for IEEE div
}
__device__ __forceinline__ unsigned short f2bf(float f) {
  unsigned int u = __float_as_uint(f);
  return (unsigned short)((u + 0x7fffu + ((u >> 16) & 1u)) >> 16);
}
__device__ __forceinline__ float cutf(float r) {
  return (r <= 6.0f) ? (0.5f * (cosf((3.14159265358979323846f * r) / 6.0f) + 1.0f)) : 0.0f;
}
__device__ __forceinline__ float rbff(float r, int i) {
  float rc = fminf(r, 6.0f);
  float c = (float)i * (6.0f / 31.0f);
  float d = rc - c;
  return expf(-26.694445f * d * d);
}
__device__ __forceinline__ void pair_jk(int p, int& j, int& k) {
  int jj = (int)((127.0 - sqrt(16129.0 - 8.0 * (double)p)) * 0.5);
  if (jj < 0) jj = 0;
  if (jj > 62) jj = 62;
  while (jj < 62 && (63 * (jj + 1) - ((jj + 1) * jj) / 2) <= p) jj++;
  while (jj > 0 && (63 * jj - (jj * (jj - 1)) / 2) > p) jj--;
  j = jj;
  k = p - (63 * jj - (jj * (jj - 1)) / 2) + jj + 1;
}

// ---- prep: z-width flag + Ae + all bf16 weight fragments (A-operand order: A[n][k])
// frag idx: [((nt*NKK + kk)*64 + lane)*8 + j] -> n = 16nt+(lane&15), k = 32kk+(lane>>4)*8+j
__global__ __launch_bounds__(256) void k_prep(
    const int* __restrict__ z, const float* __restrict__ ef,
    const float* __restrict__ pw0, const float* __restrict__ pw1,
    const float* __restrict__ pw2, const float* __restrict__ gw0,
    const float* __restrict__ gw1, const float* __restrict__ gw2, char* ws) {
  int idx = blockIdx.x * 256 + threadIdx.x;  // 0..221183
  if (idx == 0) *((int*)(ws + WS_FLAG)) = (z[1] == 0) ? 1 : 0;
  if (idx < 16384) {  // W1F: 128x128, NKK=4
    int j = idx & 7, l = (idx >> 3) & 63, t2 = idx >> 9;
    int kk = t2 & 3, nt = t2 >> 2;
    int n = 16 * nt + (l & 15), k = 32 * kk + (l >> 4) * 8 + j;
    ((unsigned short*)(ws + WS_W1F))[idx] = f2bf(pw1[k * 128 + n]);
  } else if (idx < 24576) {  // W2F: 128x64, NKK=4
    int id = idx - 16384;
    int j = id & 7, l = (id >> 3) & 63, t2 = id >> 9;
    int kk = t2 & 3, nt = t2 >> 2;
    int n = 16 * nt + (l & 15), k = 32 * kk + (l >> 4) * 8 + j;
    ((unsigned short*)(ws + WS_W2F))[id] = f2bf(pw2[k * 64 + n]);
  } else if (idx < 122880) {  // G0F: 353(->384)x256, NKK=12
    int id = idx - 24576;
    int j = id & 7, l = (id >> 3) & 63, t2 = id >> 9;  // 0..191
    int kk = t2 % 12, nt = t2 / 12;
    int n = 16 * nt + (l & 15), k = 32 * kk + (l >> 4) * 8 + j;
    float v = (k < 353) ? gw0[k * 256 + n] : 0.0f;
    ((unsigned short*)(ws + WS_G0F))[id] = f2bf(v);
  } else if (idx < 188416) {  // G1F: 256x256, NKK=8
    int id = idx - 122880;
    int j = id & 7, l = (id >> 3) & 63, t2 = id >> 9;  // 0..127
    int kk = t2 & 7, nt = t2 >> 3;
    int n = 16 * nt + (l & 15), k = 32 * kk + (l >> 4) * 8 + j;
    ((unsigned short*)(ws + WS_G1F))[id] = f2bf(gw1[k * 256 + n]);
  } else if (idx < 204800) {  // G2F: 256x64, NKK=8
    int id = idx - 188416;
    int j = id & 7, l = (id >> 3) & 63, t2 = id >> 9;  // 0..31
    int kk = t2 & 7, nt = t2 >> 3;
    int n = 16 * nt + (l & 15), k = 32 * kk + (l >> 4) * 8 + j;
    ((unsigned short*)(ws + WS_G2F))[id] = f2bf(gw2[k * 64 + n]);
  } else if (idx < 221184) {  // Ae[e][d] = e_feat[e] @ pw0[64:96]
    int id = idx - 204800;
    int e = id >> 7, d = id & 127;
    float a = 0.0f;
    for (int i = 0; i < 32; i++) a += ef[e * 32 + i] * pw0[(64 + i) * 128 + d];
    ((float*)(ws + WS_AE))[e * 128 + d] = a;
  }
}

// per-batch pair scoring + exact stable top-256 via 8-bit radix select on
// 64-bit keys (score_bits<<32 | pair_idx). Keys distinct -> selected SET
// identical to stable argsort top-256; slot order is irrelevant downstream
// (pure sum aggregation).
__global__ __launch_bounds__(256) void k1_select(const float* __restrict__ pos, char* ws) {
#pragma clang fp contract(off)
  int b = blockIdx.x, t = threadIdx.x;
  __shared__ float px[64], py[64], pz[64], rr[64];
  __shared__ int hist[256], scan[256];
  __shared__ unsigned long long selk[256];
  __shared__ float wred[256];
  __shared__ unsigned long long s_pref, s_kstar;
  __shared__ int s_K, s_done, s_digit, s_exc, s_cnt;
  if (t < 64) {
    px[t] = pos[(b * 64 + t) * 3 + 0];
    py[t] = pos[(b * 64 + t) * 3 + 1];
    pz[t] = pos[(b * 64 + t) * 3 + 2];
  }
  if (t == 0) { s_pref = 0; s_K = PSEL; s_done = 0; s_cnt = 0; }
  __syncthreads();
  if (t < 64) {
    float dx = px[t] - px[0], dy = py[t] - py[0], dz = pz[t] - pz[0];
    rr[t] = sqrtf((dx * dx + dy * dy) + dz * dz);
  }
  __syncthreads();
  // build 8 keys per thread in registers
  unsigned long long keys[8];
#pragma unroll
  for (int ii = 0; ii < 8; ii++) {
    int p = t + 256 * ii;
    unsigned long long key = 0xFFFFFFFFFFFFFFFFull;
    if (p < NPAIR) {
      int j, k;
      pair_jk(p, j, k);
      bool vj = (j != 0) && (rr[j] <= 6.0f);
      bool vk = (rr[k] <= 6.0f);
      unsigned int sb = 0x7f800000u;  // +inf
      if (vj && vk) {
        float dx = px[k] - px[j], dy = py[k] - py[j], dz = pz[k] - pz[j];
        float rjk = sqrtf((dx * dx + dy * dy) + dz * dz);
        float score = (rr[j] + rr[k]) + 0.5f * rjk;
        sb = __float_as_uint(score);
      }
      key = (((unsigned long long)sb) << 32) | (unsigned int)p;
    }
    keys[ii] = key;
  }
  // radix select: find 256th-smallest key K*
  for (int shift = 56; shift >= 0; shift -= 8) {
    if (s_done) break;  // uniform (read after barrier)
    hist[t] = 0;
    __syncthreads();
    unsigned long long hiMask = (shift == 56) ? 0ull : (~0ull << (shift + 8));
    unsigned long long pref = s_pref;
    int K = s_K;
#pragma unroll
    for (int ii = 0; ii < 8; ii++) {
      if ((keys[ii] & hiMask) == pref)
        atomicAdd(&hist[(int)((keys[ii] >> shift) & 255)], 1);
    }
    __syncthreads();
    scan[t] = hist[t];
    __syncthreads();
    for (int off = 1; off < 256; off <<= 1) {
      int add = (t >= off) ? scan[t - off] : 0;
      __syncthreads();
      scan[t] += add;
      __syncthreads();
    }
    int inc = scan[t], exc = inc - hist[t];
    if (exc < K && K <= inc) { s_digit = t; s_exc = exc; }
    __syncthreads();
    int d = s_digit, exc2 = s_exc, cnt = hist[d];
    unsigned long long npref = pref | ((unsigned long long)d << shift);
    if (cnt == 1) {
      unsigned long long inclMask = hiMask | (255ull << shift);
#pragma unroll
      for (int ii = 0; ii < 8; ii++)
        if ((keys[ii] & inclMask) == npref) s_kstar = keys[ii];
      if (t == 0) s_done = 1;
    } else if (shift == 0) {
      if (t == 0) { s_kstar = npref; s_done = 1; }
    } else {
      if (t == 0) { s_pref = npref; s_K = K - exc2; }
    }
    __syncthreads();
  }
  unsigned long long kstar = s_kstar;
  // gather the 256 keys <= K* (exactly 256; keys are distinct)
#pragma unroll
  for (int ii = 0; ii < 8; ii++) {
    if (keys[ii] <= kstar) {
      int slot = atomicAdd(&s_cnt, 1);
      selk[slot] = keys[ii];
    }
  }
  __syncthreads();
  // per-slot geometry (identical formulas to the sorted version)
  float myw = 0.0f;
  {
    unsigned long long key = selk[t];
    unsigned int sb = (unsigned int)(key >> 32);
    int p = (int)(key & 0xFFFFFFFFu);
    bool pv = (sb < 0x7f800000u);
    int j = 0, k = 0;
    if (pv) pair_jk(p, j, k);
    float r0j = rr[j], r0k = rr[k];
    float vjx = px[j] - px[0], vjy = py[j] - py[0], vjz = pz[j] - pz[0];
    float vkx = px[k] - px[0], vky = py[k] - py[0], vkz = pz[k] - pz[0];
    float dx = px[k] - px[j], dy = py[k] - py[j], dz = pz[k] - pz[j];
    float rjk = sqrtf((dx * dx + dy * dy) + dz * dz);
    float ij = 1.0f / fmaxf(r0j, 1e-8f);
    float ik = 1.0f / fmaxf(r0k, 1e-8f);
    float cs = (vjx * vkx + vjy * vky + vjz * vkz) * ij * ik;
    cs = fminf(1.0f, fmaxf(-1.0f, cs));
    float w = pv ? (cutf(r0j) * cutf(r0k) * cutf(rjk)) : 0.0f;
    int* selJ = (int*)(ws + WS_SELJ);
    int* selK = (int*)(ws + WS_SELK);
    float* scal = (float*)(ws + WS_SCAL);
    selJ[b * PSEL + t] = j;
    selK[b * PSEL + t] = k;
    float* s = &scal[(b * PSEL + t) * 8];
    s[0] = r0j; s[1] = r0k; s[2] = rjk; s[3] = cs; s[4] = w;
    myw = w;
  }
  wred[t] = myw;
  __syncthreads();
  for (int s2 = 128; s2 > 0; s2 >>= 1) {
    if (t < s2) wred[t] += wred[t + s2];
    __syncthreads();
  }
  if (t == 0) ((float*)(ws + WS_SUMW))[b] = fmaxf(wred[0], 1e-8f);
}

// A0[b,p][d] = z_emb[zj]@pw0[0:32] + z_emb[zk]@pw0[32:64] + pb0
__global__ __launch_bounds__(128) void k2b_a0(const int* __restrict__ z,
                                              const float* __restrict__ zemb,
                                              const float* __restrict__ pw0,
                                              const float* __restrict__ pb0, char* ws) {
  int p = blockIdx.x, b = blockIdx.y, d = threadIdx.x;
  const int* selJ = (const int*)(ws + WS_SELJ);
  const int* selK = (const int*)(ws + WS_SELK);
  int is64 = *((const int*)(ws + WS_FLAG));
  float* A0 = (float*)(ws + WS_A0);
  int j = selJ[b * PSEL + p], k = selK[b * PSEL + p];
  __shared__ float zr[64];
  if (d < 64) {
    int atom = (d < 32) ? j : k;
    int zi = b * 64 + atom;
    int zv = is64 ? z[zi * 2] : z[zi];
    zr[d] = zemb[zv * 32 + (d & 31)];
  }
  __syncthreads();
  float a = pb0[d];
  for (int i = 0; i < 32; i++) {
    a += zr[i] * pw0[i * 128 + d];
    a += zr[32 + i] * pw0[(32 + i) * 128 + d];
  }
  A0[(b * PSEL + p) * 128 + d] = a;
}

// geom MLP via bf16 MFMA: 353(pad384)->256->256->64, folds w/sumw into gg
#define LP3 392  // xs row stride (bf16): 196 dw, /4=49 odd -> uniform b128 bank spread
#define LQ3 264  // x1s/x2s row stride: 132 dw, /4=33 odd
__global__ __launch_bounds__(256) void k3_geom(const float* __restrict__ h,
    const float* __restrict__ gb0, const float* __restrict__ gb1,
    const float* __restrict__ gb2, char* ws) {
  int blk = blockIdx.x;
  int b = blk >> 4, p0 = (blk & 15) * 16;
  int t = threadIdx.x;
  int lane = t & 63, w = t >> 6;
  int q = lane >> 4, m4 = lane & 15;
  const int* selJ = (const int*)(ws + WS_SELJ);
  const int* selK = (const int*)(ws + WS_SELK);
  const float* scal = (const float*)(ws + WS_SCAL);
  const float* sumw = (const float*)(ws + WS_SUMW);
  float* gg = (float*)(ws + WS_GG);
  const unsigned short* G0F = (const unsigned short*)(ws + WS_G0F);
  const unsigned short* G1F = (const unsigned short*)(ws + WS_G1F);
  const unsigned short* G2F = (const unsigned short*)(ws + WS_G2F);
  __shared__ __align__(16) unsigned short xs[16 * LP3];
  __shared__ __align__(16) unsigned short x1s[16 * LQ3];
  __shared__ __align__(16) unsigned short x2s[16 * LQ3];
  const v4f z4 = {0.f, 0.f, 0.f, 0.f};
  {  // stage X[row][f], f in [0,384)
    int row = t & 15, fs = t >> 4;
    int p = p0 + row;
    int j = selJ[b * PSEL + p], k = selK[b * PSEL + p];
    const float* s = &scal[(b * PSEL + p) * 8];
    float r0j = s[0], r0k = s[1], rjk = s[2], cs = s[3];
    for (int f = fs; f < 384; f += 16) {
      float v;
      if (f < 128) v = h[(b * 64 + j) * 128 + f];
      else if (f < 256) v = h[(b * 64 + k) * 128 + (f - 128)];
      else if (f < 288) v = rbff(r0j, f - 256);
      else if (f < 320) v = rbff(r0k, f - 288);
      else if (f < 352) v = rbff(rjk, f - 320);
      else if (f == 352) v = cs;
      else v = 0.0f;
      xs[row * LP3 + f] = f2bf(v);
    }
  }
  __syncthreads();
  {  // L1: out 16 x 256 (wave w: cols 64w..64w+63), K=384
    v4f acc[4];
#pragma unroll
    for (int nt = 0; nt < 4; nt++) acc[nt] = z4;
    for (int kk = 0; kk < 12; kk++) {
      v8s bf = *(const v8s*)&xs[m4 * LP3 + 32 * kk + 8 * q];
#pragma unroll
      for (int nt = 0; nt < 4; nt++) {
        v8s wf = *(const v8s*)&G0F[(((4 * w + nt) * 12 + kk) * 64 + lane) * 8];
        acc[nt] = __builtin_amdgcn_mfma_f32_16x16x32_bf16(wf, bf, acc[nt], 0, 0, 0);
      }
    }
#pragma unroll
    for (int nt = 0; nt < 4; nt++) {
      int n0 = 64 * w + 16 * nt + 4 * q;
      float4 bias = *(const float4*)&gb0[n0];
      short4 o;
      o.x = (short)f2bf(siluf_fast(acc[nt][0] + bias.x));
      o.y = (short)f2bf(siluf_fast(acc[nt][1] + bias.y));
      o.z = (short)f2bf(siluf_fast(acc[nt][2] + bias.z));
      o.w = (short)f2bf(siluf_fast(acc[nt][3] + bias.w));
      *(short4*)&x1s[m4 * LQ3 + n0] = o;
    }
  }
  __syncthreads();
  {  // L2: out 16 x 256, K=256
    v4f acc[4];
#pragma unroll
    for (int nt = 0; nt < 4; nt++) acc[nt] = z4;
    for (int kk = 0; kk < 8; kk++) {
      v8s bf = *(const v8s*)&x1s[m4 * LQ3 + 32 * kk + 8 * q];
#pragma unroll
      for (int nt = 0; nt < 4; nt++) {
        v8s wf = *(const v8s*)&G1F[(((4 * w + nt) * 8 + kk) * 64 + lane) * 8];
        acc[nt] = __builtin_amdgcn_mfma_f32_16x16x32_bf16(wf, bf, acc[nt], 0, 0, 0);
      }
    }
#pragma unroll
    for (int nt = 0; nt < 4; nt++) {
      int n0 = 64 * w + 16 * nt + 4 * q;
      float4 bias = *(const float4*)&gb1[n0];
      short4 o;
      o.x = (short)f2bf(siluf_fast(acc[nt][0] + bias.x));
      o.y = (short)f2bf(siluf_fast(acc[nt][1] + bias.y));
      o.z = (short)f2bf(siluf_fast(acc[nt][2] + bias.z));
      o.w = (short)f2bf(siluf_fast(acc[nt][3] + bias.w));
      *(short4*)&x2s[m4 * LQ3 + n0] = o;
    }
  }
  __syncthreads();
  {  // L3: out 16 x 64 (wave w: cols 16w..16w+15), K=256, linear + fold w/norm
    v4f acc = z4;
    for (int kk = 0; kk < 8; kk++) {
      v8s bf = *(const v8s*)&x2s[m4 * LQ3 + 32 * kk + 8 * q];
      v8s wf = *(const v8s*)&G2F[((w * 8 + kk) * 64 + lane) * 8];
      acc = __builtin_amdgcn_mfma_f32_16x16x32_bf16(wf, bf, acc, 0, 0, 0);
    }
    int p = p0 + m4;
    float wp = scal[(b * PSEL + p) * 8 + 4];
    float s2 = wp / sumw[b];
    int n0 = 16 * w + 4 * q;
    float4 bias = *(const float4*)&gb2[n0];
    float4 o;
    o.x = (acc[0] + bias.x) * s2;
    o.y = (acc[1] + bias.y) * s2;
    o.z = (acc[2] + bias.z) * s2;
    o.w = (acc[3] + bias.w) * s2;
    *(float4*)&gg[(b * PSEL + p) * 64 + n0] = o;
  }
}

// fused elem MLP via bf16 MFMA: X1 = silu((W1^T . X0^T)^T), Y = (W2^T . X1^T)^T
#define LP 136  // padded LDS row stride (bf16); 68 dw, /4=17 odd -> uniform bank spread
__global__ __launch_bounds__(256, 4) void k4_elem(
    const float* __restrict__ pb1, const float* __restrict__ pb2, char* ws) {
  int pc = blockIdx.x, et = blockIdx.y, b = blockIdx.z;
  int t = threadIdx.x;
  int lane = t & 63, w = t >> 6;
  int q = lane >> 4, m4 = lane & 15;
  const float* A0 = (const float*)(ws + WS_A0);
  const float* Ae = (const float*)(ws + WS_AE);
  const float* gg = (const float*)(ws + WS_GG);
  const unsigned short* W1F = (const unsigned short*)(ws + WS_W1F);
  const unsigned short* W2F = (const unsigned short*)(ws + WS_W2F);
  float* agg = (float*)(ws + WS_AGG);
  __shared__ __align__(16) unsigned short x0s[64 * LP];
  __shared__ __align__(16) unsigned short x1s[64 * LP];
  int e0 = et * 8;

  v8s w1f[2][4], w2f[4];
#pragma unroll
  for (int ct = 0; ct < 2; ct++)
#pragma unroll
    for (int kk = 0; kk < 4; kk++)
      w1f[ct][kk] = *(const v8s*)&W1F[(((2 * w + ct) * 4 + kk) * 64 + lane) * 8];
#pragma unroll
  for (int kk = 0; kk < 4; kk++)
    w2f[kk] = *(const v8s*)&W2F[(((w) * 4 + kk) * 64 + lane) * 8];
  float4 b1v[2];
  b1v[0] = *(const float4*)&pb1[32 * w + 4 * q];
  b1v[1] = *(const float4*)&pb1[32 * w + 16 + 4 * q];
  float4 b2v = *(const float4*)&pb2[16 * w + 4 * q];

  v4f aggR[4];
  const v4f z4 = {0.f, 0.f, 0.f, 0.f};
#pragma unroll
  for (int mt = 0; mt < 4; mt++) aggR[mt] = z4;

  for (int g2 = 0; g2 < 8; g2++) {
    int pbase = pc * 64 + g2 * 8;
#pragma unroll
    for (int it = 0; it < 8; it++) {
      int flat = it * 1024 + t * 4;
      int m = flat >> 7, k = flat & 127;
      int pl = m & 7, e = m >> 3;
      float4 a0v = *(const float4*)&A0[(b * PSEL + pbase + pl) * 128 + k];
      float4 aev = *(const float4*)&Ae[(e0 + e) * 128 + k];
      short4 o;
      o.x = (short)f2bf(siluf_fast(a0v.x + aev.x));
      o.y = (short)f2bf(siluf_fast(a0v.y + aev.y));
      o.z = (short)f2bf(siluf_fast(a0v.z + aev.z));
      o.w = (short)f2bf(siluf_fast(a0v.w + aev.w));
      *(short4*)&x0s[m * LP + k] = o;
    }
    __syncthreads();
    v4f acc1[4][2];
#pragma unroll
    for (int mt = 0; mt < 4; mt++) { acc1[mt][0] = z4; acc1[mt][1] = z4; }
#pragma unroll
    for (int kk = 0; kk < 4; kk++) {
#pragma unroll
      for (int mt = 0; mt < 4; mt++) {
        v8s bf = *(const v8s*)&x0s[(16 * mt + m4) * LP + 32 * kk + 8 * q];
        acc1[mt][0] = __builtin_amdgcn_mfma_f32_16x16x32_bf16(w1f[0][kk], bf, acc1[mt][0], 0, 0, 0);
        acc1[mt][1] = __builtin_amdgcn_mfma_f32_16x16x32_bf16(w1f[1][kk], bf, acc1[mt][1], 0, 0, 0);
      }
    }
#pragma unroll
    for (int mt = 0; mt < 4; mt++) {
#pragma unroll
      for (int ct = 0; ct < 2; ct++) {
        float4 bias = b1v[ct];
        short4 o;
        o.x = (short)f2bf(siluf_fast(acc1[mt][ct][0] + bias.x));
        o.y = (short)f2bf(siluf_fast(acc1[mt][ct][1] + bias.y));
        o.z = (short)f2bf(siluf_fast(acc1[mt][ct][2] + bias.z));
        o.w = (short)f2bf(siluf_fast(acc1[mt][ct][3] + bias.w));
        int n0 = 32 * w + 16 * ct + 4 * q;
        *(short4*)&x1s[(16 * mt + m4) * LP + n0] = o;
      }
    }
    __syncthreads();
    v4f acc2[4];
#pragma unroll
    for (int mt = 0; mt < 4; mt++) acc2[mt] = z4;
#pragma unroll
    for (int kk = 0; kk < 4; kk++) {
#pragma unroll
      for (int mt = 0; mt < 4; mt++) {
        v8s bf = *(const v8s*)&x1s[(16 * mt + m4) * LP + 32 * kk + 8 * q];
        acc2[mt] = __builtin_amdgcn_mfma_f32_16x16x32_bf16(w2f[kk], bf, acc2[mt], 0, 0, 0);
      }
    }
    float4 gv = *(const float4*)&gg[(b * PSEL + pbase + (lane & 7)) * 64 + 16 * w + 4 * q];
#pragma unroll
    for (int mt = 0; mt < 4; mt++) {
      aggR[mt][0] += gv.x * (acc2[mt][0] + b2v.x);
      aggR[mt][1] += gv.y * (acc2[mt][1] + b2v.y);
      aggR[mt][2] += gv.z * (acc2[mt][2] + b2v.z);
      aggR[mt][3] += gv.w * (acc2[mt][3] + b2v.w);
    }
  }
#pragma unroll
  for (int mt = 0; mt < 4; mt++) {
#pragma unroll
    for (int r = 0; r < 4; r++) {
      float v = aggR[mt][r];
      v += __shfl_xor(v, 1);
      v += __shfl_xor(v, 2);
      v += __shfl_xor(v, 4);
      if ((lane & 7) == 0) {
        int e = 2 * mt + ((lane >> 3) & 1);
        int n = 16 * w + 4 * q + r;
        atomicAdd(&agg[(b * NEL + e0 + e) * 64 + n], v);
      }
    }
  }
}

// output MLP 64->256 silu ->128 (f32 vector; small)
__global__ __launch_bounds__(256) void k5_out(
    const float* __restrict__ ow0, const float* __restrict__ ob0,
    const float* __restrict__ ow1, const float* __restrict__ ob1,
    const char* ws, float* __restrict__ out) {
  int row0 = blockIdx.x * 16;
  int t = threadIdx.x;
  const float* agg = (const float*)(ws + WS_AGG);
  __shared__ float xT[64][16];
  __shared__ float x1T[256][16];
  {
    int row = t & 15, fs = t >> 4;
    for (int f = fs; f < 64; f += 16) xT[f][row] = agg[(row0 + row) * 64 + f];
  }
  __syncthreads();
  {
    int r0 = (t & 3) * 4, c0 = (t >> 2) * 4;
    float acc[4][4] = {};
    for (int k2 = 0; k2 < 64; k2++) {
      float4 xv = *(const float4*)&xT[k2][r0];
      float4 wv = *(const float4*)&ow0[k2 * 256 + c0];
      float xs2[4] = {xv.x, xv.y, xv.z, xv.w};
      float wss[4] = {wv.x, wv.y, wv.z, wv.w};
#pragma unroll
      for (int i = 0; i < 4; i++)
#pragma unroll
        for (int j2 = 0; j2 < 4; j2++) acc[i][j2] += xs2[i] * wss[j2];
    }
#pragma unroll
    for (int jj = 0; jj < 4; jj++) {
      float bias = ob0[c0 + jj];
#pragma unroll
      for (int i = 0; i < 4; i++) x1T[c0 + jj][r0 + i] = siluf_fast(acc[i][jj] + bias);
    }
  }
  __syncthreads();
  {
    int r0 = (t & 3) * 4, c0 = (t >> 2) * 2;
    float acc[4][2] = {};
    for (int k2 = 0; k2 < 256; k2++) {
      float4 xv = *(const float4*)&x1T[k2][r0];
      float2 wv = *(const float2*)&ow1[k2 * 128 + c0];
      float xs2[4] = {xv.x, xv.y, xv.z, xv.w};
#pragma unroll
      for (int i = 0; i < 4; i++) {
        acc[i][0] += xs2[i] * wv.x;
        acc[i][1] += xs2[i] * wv.y;
      }
    }
#pragma unroll
    for (int i = 0; i < 4; i++)
#pragma unroll
      for (int j2 = 0; j2 < 2; j2++)
        out[(row0 + r0 + i) * 128 + c0 + j2] = acc[i][j2] + ob1[c0 + j2];
  }
}

extern "C" void kernel_launch(void* const* d_in, const int* in_sizes, int n_in,
                              void* d_out, int out_size, void* d_ws, size_t ws_size,
                              hipStream_t stream) {
  const float* h     = (const float*)d_in[0];
  const int*   z     = (const int*)d_in[1];
  const float* pos   = (const float*)d_in[2];
  const float* efeat = (const float*)d_in[4];
  const float* zemb  = (const float*)d_in[5];
  const float* pw0 = (const float*)d_in[6];
  const float* pb0 = (const float*)d_in[7];
  const float* pw1 = (const float*)d_in[8];
  const float* pb1 = (const float*)d_in[9];
  const float* pw2 = (const float*)d_in[10];
  const float* pb2 = (const float*)d_in[11];
  const float* gw0 = (const float*)d_in[12];
  const float* gb0 = (const float*)d_in[13];
  const float* gw1 = (const float*)d_in[14];
  const float* gb1 = (const float*)d_in[15];
  const float* gw2 = (const float*)d_in[16];
  const float* gb2 = (const float*)d_in[17];
  const float* ow0 = (const float*)d_in[18];
  const float* ob0 = (const float*)d_in[19];
  const float* ow1 = (const float*)d_in[20];
  const float* ob1 = (const float*)d_in[21];
  char* ws = (char*)d_ws;
  float* out = (float*)d_out;

  hipMemsetAsync(ws + WS_AGG, 0, NB * NEL * 64 * sizeof(float), stream);
  k_prep<<<864, 256, 0, stream>>>(z, efeat, pw0, pw1, pw2, gw0, gw1, gw2, ws);
  k1_select<<<16, 256, 0, stream>>>(pos, ws);
  k2b_a0<<<dim3(256, 16), 128, 0, stream>>>(z, zemb, pw0, pb0, ws);
  k3_geom<<<256, 256, 0, stream>>>(h, gb0, gb1, gb2, ws);
  k4_elem<<<dim3(4, 16, 16), 256, 0, stream>>>(pb1, pb2, ws);
  k5_out<<<128, 256, 0, stream>>>(ow0, ob0, ow1, ob1, ws, out);
}

// Round 5
// 229.563 us; speedup vs baseline: 3.1862x; 1.1017x over previous
//
#include <hip/hip_runtime.h>
#include <math.h>

#define NB 16
#define NA 64
#define NHD 128
#define NPAIR 2016
#define PSEL 256
#define NEL 128
// ws byte offsets (all 256-aligned)
#define WS_FLAG   0
#define WS_SUMW   1024
#define WS_SELJ   2048
#define WS_SELK   (WS_SELJ + 16384)
#define WS_SCAL   (WS_SELK + 16384)      // [4096][8] f32
#define WS_AE     (WS_SCAL + 131072)     // [128][128] f32
#define WS_GG     (WS_AE + 65536)        // [4096][64] f32
#define WS_A0     (WS_GG + 1048576)      // [4096][128] f32
#define WS_AGG    (WS_A0 + 2097152)      // [16][128][64] f32
#define WS_W1F    (WS_AGG + 524288)      // bf16 frag pw1, 32KB
#define WS_W2F    (WS_W1F + 32768)       // bf16 frag pw2, 16KB
#define WS_G0F    (WS_W2F + 16384)       // bf16 frag gw0 (K padded 384), 192KB
#define WS_G1F    (WS_G0F + 196608)      // bf16 frag gw1, 128KB
#define WS_G2F    (WS_G1F + 131072)      // bf16 frag gw2, 32KB

typedef short v8s __attribute__((ext_vector_type(8)));
typedef float v4f __attribute__((ext_vector_type(4)));

__device__ __forceinline__ float siluf_fast(float x) {
  float e = __expf(-x);
  return x * __builtin_amdgcn_rcpf(1.0f + e);  // v_rcp_f32: ~1ulp
}
__device__ __forceinline__ unsigned short f2bf(float f) {
  unsigned int u = __float_as_uint(f);
  return (unsigned short)((u + 0x7fffu + ((u >> 16) & 1u)) >> 16);
}
// pack two f32 -> bf16x2 (RNE, bit-identical to f2bf): v_bfe+v_add3 x2 + v_perm
__device__ __forceinline__ unsigned int pk_bf16(float fa, float fb) {
  unsigned int ua = __float_as_uint(fa), ub = __float_as_uint(fb);
  ua = ua + 0x7fffu + ((ua >> 16) & 1u);
  ub = ub + 0x7fffu + ((ub >> 16) & 1u);
  return __builtin_amdgcn_perm(ub, ua, 0x07060302u);  // [ub.hi16 : ua.hi16]
}
__device__ __forceinline__ float cutf(float r) {
  return (r <= 6.0f) ? (0.5f * (cosf((3.14159265358979323846f * r) / 6.0f) + 1.0f)) : 0.0f;
}
__device__ __forceinline__ float rbff(float r, int i) {
  float rc = fminf(r, 6.0f);
  float c = (float)i * (6.0f / 31.0f);
  float d = rc - c;
  return expf(-26.694445f * d * d);
}
__device__ __forceinline__ void pair_jk(int p, int& j, int& k) {
  int jj = (int)((127.0 - sqrt(16129.0 - 8.0 * (double)p)) * 0.5);
  if (jj < 0) jj = 0;
  if (jj > 62) jj = 62;
  while (jj < 62 && (63 * (jj + 1) - ((jj + 1) * jj) / 2) <= p) jj++;
  while (jj > 0 && (63 * jj - (jj * (jj - 1)) / 2) > p) jj--;
  j = jj;
  k = p - (63 * jj - (jj * (jj - 1)) / 2) + jj + 1;
}

// ---- prep: z-width flag + Ae + all bf16 weight fragments (A-operand order: A[n][k])
__global__ __launch_bounds__(256) void k_prep(
    const int* __restrict__ z, const float* __restrict__ ef,
    const float* __restrict__ pw0, const float* __restrict__ pw1,
    const float* __restrict__ pw2, const float* __restrict__ gw0,
    const float* __restrict__ gw1, const float* __restrict__ gw2, char* ws) {
  int idx = blockIdx.x * 256 + threadIdx.x;  // 0..221183
  if (idx == 0) *((int*)(ws + WS_FLAG)) = (z[1] == 0) ? 1 : 0;
  if (idx < 16384) {  // W1F: 128x128, NKK=4
    int j = idx & 7, l = (idx >> 3) & 63, t2 = idx >> 9;
    int kk = t2 & 3, nt = t2 >> 2;
    int n = 16 * nt + (l & 15), k = 32 * kk + (l >> 4) * 8 + j;
    ((unsigned short*)(ws + WS_W1F))[idx] = f2bf(pw1[k * 128 + n]);
  } else if (idx < 24576) {  // W2F: 128x64, NKK=4
    int id = idx - 16384;
    int j = id & 7, l = (id >> 3) & 63, t2 = id >> 9;
    int kk = t2 & 3, nt = t2 >> 2;
    int n = 16 * nt + (l & 15), k = 32 * kk + (l >> 4) * 8 + j;
    ((unsigned short*)(ws + WS_W2F))[id] = f2bf(pw2[k * 64 + n]);
  } else if (idx < 122880) {  // G0F: 353(->384)x256, NKK=12
    int id = idx - 24576;
    int j = id & 7, l = (id >> 3) & 63, t2 = id >> 9;  // 0..191
    int kk = t2 % 12, nt = t2 / 12;
    int n = 16 * nt + (l & 15), k = 32 * kk + (l >> 4) * 8 + j;
    float v = (k < 353) ? gw0[k * 256 + n] : 0.0f;
    ((unsigned short*)(ws + WS_G0F))[id] = f2bf(v);
  } else if (idx < 188416) {  // G1F: 256x256, NKK=8
    int id = idx - 122880;
    int j = id & 7, l = (id >> 3) & 63, t2 = id >> 9;  // 0..127
    int kk = t2 & 7, nt = t2 >> 3;
    int n = 16 * nt + (l & 15), k = 32 * kk + (l >> 4) * 8 + j;
    ((unsigned short*)(ws + WS_G1F))[id] = f2bf(gw1[k * 256 + n]);
  } else if (idx < 204800) {  // G2F: 256x64, NKK=8
    int id = idx - 188416;
    int j = id & 7, l = (id >> 3) & 63, t2 = id >> 9;  // 0..31
    int kk = t2 & 7, nt = t2 >> 3;
    int n = 16 * nt + (l & 15), k = 32 * kk + (l >> 4) * 8 + j;
    ((unsigned short*)(ws + WS_G2F))[id] = f2bf(gw2[k * 64 + n]);
  } else if (idx < 221184) {  // Ae[e][d] = e_feat[e] @ pw0[64:96]
    int id = idx - 204800;
    int e = id >> 7, d = id & 127;
    float a = 0.0f;
    for (int i = 0; i < 32; i++) a += ef[e * 32 + i] * pw0[(64 + i) * 128 + d];
    ((float*)(ws + WS_AE))[e * 128 + d] = a;
  }
}

// per-batch pair scoring + exact stable top-256 via 8-bit radix select on
// 64-bit keys (score_bits<<32 | pair_idx). Keys distinct -> selected SET
// identical to stable argsort top-256; slot order irrelevant downstream.
__global__ __launch_bounds__(256) void k1_select(const float* __restrict__ pos, char* ws) {
#pragma clang fp contract(off)
  int b = blockIdx.x, t = threadIdx.x;
  __shared__ float px[64], py[64], pz[64], rr[64];
  __shared__ int hist[256], scan[256];
  __shared__ unsigned long long selk[256];
  __shared__ float wred[256];
  __shared__ unsigned long long s_pref, s_kstar;
  __shared__ int s_K, s_done, s_digit, s_exc, s_cnt;
  if (t < 64) {
    px[t] = pos[(b * 64 + t) * 3 + 0];
    py[t] = pos[(b * 64 + t) * 3 + 1];
    pz[t] = pos[(b * 64 + t) * 3 + 2];
  }
  if (t == 0) { s_pref = 0; s_K = PSEL; s_done = 0; s_cnt = 0; }
  __syncthreads();
  if (t < 64) {
    float dx = px[t] - px[0], dy = py[t] - py[0], dz = pz[t] - pz[0];
    rr[t] = sqrtf((dx * dx + dy * dy) + dz * dz);
  }
  __syncthreads();
  unsigned long long keys[8];
#pragma unroll
  for (int ii = 0; ii < 8; ii++) {
    int p = t + 256 * ii;
    unsigned long long key = 0xFFFFFFFFFFFFFFFFull;
    if (p < NPAIR) {
      int j, k;
      pair_jk(p, j, k);
      bool vj = (j != 0) && (rr[j] <= 6.0f);
      bool vk = (rr[k] <= 6.0f);
      unsigned int sb = 0x7f800000u;  // +inf
      if (vj && vk) {
        float dx = px[k] - px[j], dy = py[k] - py[j], dz = pz[k] - pz[j];
        float rjk = sqrtf((dx * dx + dy * dy) + dz * dz);
        float score = (rr[j] + rr[k]) + 0.5f * rjk;
        sb = __float_as_uint(score);
      }
      key = (((unsigned long long)sb) << 32) | (unsigned int)p;
    }
    keys[ii] = key;
  }
  for (int shift = 56; shift >= 0; shift -= 8) {
    if (s_done) break;
    hist[t] = 0;
    __syncthreads();
    unsigned long long hiMask = (shift == 56) ? 0ull : (~0ull << (shift + 8));
    unsigned long long pref = s_pref;
    int K = s_K;
#pragma unroll
    for (int ii = 0; ii < 8; ii++) {
      if ((keys[ii] & hiMask) == pref)
        atomicAdd(&hist[(int)((keys[ii] >> shift) & 255)], 1);
    }
    __syncthreads();
    scan[t] = hist[t];
    __syncthreads();
    for (int off = 1; off < 256; off <<= 1) {
      int add = (t >= off) ? scan[t - off] : 0;
      __syncthreads();
      scan[t] += add;
      __syncthreads();
    }
    int inc = scan[t], exc = inc - hist[t];
    if (exc < K && K <= inc) { s_digit = t; s_exc = exc; }
    __syncthreads();
    int d = s_digit, exc2 = s_exc, cnt = hist[d];
    unsigned long long npref = pref | ((unsigned long long)d << shift);
    if (cnt == 1) {
      unsigned long long inclMask = hiMask | (255ull << shift);
#pragma unroll
      for (int ii = 0; ii < 8; ii++)
        if ((keys[ii] & inclMask) == npref) s_kstar = keys[ii];
      if (t == 0) s_done = 1;
    } else if (shift == 0) {
      if (t == 0) { s_kstar = npref; s_done = 1; }
    } else {
      if (t == 0) { s_pref = npref; s_K = K - exc2; }
    }
    __syncthreads();
  }
  unsigned long long kstar = s_kstar;
#pragma unroll
  for (int ii = 0; ii < 8; ii++) {
    if (keys[ii] <= kstar) {
      int slot = atomicAdd(&s_cnt, 1);
      selk[slot] = keys[ii];
    }
  }
  __syncthreads();
  float myw = 0.0f;
  {
    unsigned long long key = selk[t];
    unsigned int sb = (unsigned int)(key >> 32);
    int p = (int)(key & 0xFFFFFFFFu);
    bool pv = (sb < 0x7f800000u);
    int j = 0, k = 0;
    if (pv) pair_jk(p, j, k);
    float r0j = rr[j], r0k = rr[k];
    float vjx = px[j] - px[0], vjy = py[j] - py[0], vjz = pz[j] - pz[0];
    float vkx = px[k] - px[0], vky = py[k] - py[0], vkz = pz[k] - pz[0];
    float dx = px[k] - px[j], dy = py[k] - py[j], dz = pz[k] - pz[j];
    float rjk = sqrtf((dx * dx + dy * dy) + dz * dz);
    float ij = 1.0f / fmaxf(r0j, 1e-8f);
    float ik = 1.0f / fmaxf(r0k, 1e-8f);
    float cs = (vjx * vkx + vjy * vky + vjz * vkz) * ij * ik;
    cs = fminf(1.0f, fmaxf(-1.0f, cs));
    float w = pv ? (cutf(r0j) * cutf(r0k) * cutf(rjk)) : 0.0f;
    int* selJ = (int*)(ws + WS_SELJ);
    int* selK = (int*)(ws + WS_SELK);
    float* scal = (float*)(ws + WS_SCAL);
    selJ[b * PSEL + t] = j;
    selK[b * PSEL + t] = k;
    float* s = &scal[(b * PSEL + t) * 8];
    s[0] = r0j; s[1] = r0k; s[2] = rjk; s[3] = cs; s[4] = w;
    myw = w;
  }
  wred[t] = myw;
  __syncthreads();
  for (int s2 = 128; s2 > 0; s2 >>= 1) {
    if (t < s2) wred[t] += wred[t + s2];
    __syncthreads();
  }
  if (t == 0) ((float*)(ws + WS_SUMW))[b] = fmaxf(wred[0], 1e-8f);
}

// A0[b,p][d] = z_emb[zj]@pw0[0:32] + z_emb[zk]@pw0[32:64] + pb0
__global__ __launch_bounds__(128) void k2b_a0(const int* __restrict__ z,
                                              const float* __restrict__ zemb,
                                              const float* __restrict__ pw0,
                                              const float* __restrict__ pb0, char* ws) {
  int p = blockIdx.x, b = blockIdx.y, d = threadIdx.x;
  const int* selJ = (const int*)(ws + WS_SELJ);
  const int* selK = (const int*)(ws + WS_SELK);
  int is64 = *((const int*)(ws + WS_FLAG));
  float* A0 = (float*)(ws + WS_A0);
  int j = selJ[b * PSEL + p], k = selK[b * PSEL + p];
  __shared__ float zr[64];
  if (d < 64) {
    int atom = (d < 32) ? j : k;
    int zi = b * 64 + atom;
    int zv = is64 ? z[zi * 2] : z[zi];
    zr[d] = zemb[zv * 32 + (d & 31)];
  }
  __syncthreads();
  float a = pb0[d];
  for (int i = 0; i < 32; i++) {
    a += zr[i] * pw0[i * 128 + d];
    a += zr[32 + i] * pw0[(32 + i) * 128 + d];
  }
  A0[(b * PSEL + p) * 128 + d] = a;
}

// geom MLP via bf16 MFMA: 353(pad384)->256->256->64, folds w/sumw into gg
#define LP3 392  // xs row stride (bf16)
#define LQ3 264  // x1s/x2s row stride
__global__ __launch_bounds__(256) void k3_geom(const float* __restrict__ h,
    const float* __restrict__ gb0, const float* __restrict__ gb1,
    const float* __restrict__ gb2, char* ws) {
  int blk = blockIdx.x;
  int b = blk >> 4, p0 = (blk & 15) * 16;
  int t = threadIdx.x;
  int lane = t & 63, w = t >> 6;
  int q = lane >> 4, m4 = lane & 15;
  const int* selJ = (const int*)(ws + WS_SELJ);
  const int* selK = (const int*)(ws + WS_SELK);
  const float* scal = (const float*)(ws + WS_SCAL);
  const float* sumw = (const float*)(ws + WS_SUMW);
  float* gg = (float*)(ws + WS_GG);
  const unsigned short* G0F = (const unsigned short*)(ws + WS_G0F);
  const unsigned short* G1F = (const unsigned short*)(ws + WS_G1F);
  const unsigned short* G2F = (const unsigned short*)(ws + WS_G2F);
  __shared__ __align__(16) unsigned short xs[16 * LP3];
  __shared__ __align__(16) unsigned short x1s[16 * LQ3];
  __shared__ __align__(16) unsigned short x2s[16 * LQ3];
  const v4f z4 = {0.f, 0.f, 0.f, 0.f};
  {  // stage X[row][f], f in [0,384)
    int row = t & 15, fs = t >> 4;
    int p = p0 + row;
    int j = selJ[b * PSEL + p], k = selK[b * PSEL + p];
    const float* s = &scal[(b * PSEL + p) * 8];
    float r0j = s[0], r0k = s[1], rjk = s[2], cs = s[3];
    for (int f = fs; f < 384; f += 16) {
      float v;
      if (f < 128) v = h[(b * 64 + j) * 128 + f];
      else if (f < 256) v = h[(b * 64 + k) * 128 + (f - 128)];
      else if (f < 288) v = rbff(r0j, f - 256);
      else if (f < 320) v = rbff(r0k, f - 288);
      else if (f < 352) v = rbff(rjk, f - 320);
      else if (f == 352) v = cs;
      else v = 0.0f;
      xs[row * LP3 + f] = f2bf(v);
    }
  }
  __syncthreads();
  {  // L1: out 16 x 256 (wave w: cols 64w..64w+63), K=384
    v4f acc[4];
#pragma unroll
    for (int nt = 0; nt < 4; nt++) acc[nt] = z4;
    for (int kk = 0; kk < 12; kk++) {
      v8s bf = *(const v8s*)&xs[m4 * LP3 + 32 * kk + 8 * q];
#pragma unroll
      for (int nt = 0; nt < 4; nt++) {
        v8s wf = *(const v8s*)&G0F[(((4 * w + nt) * 12 + kk) * 64 + lane) * 8];
        acc[nt] = __builtin_amdgcn_mfma_f32_16x16x32_bf16(wf, bf, acc[nt], 0, 0, 0);
      }
    }
#pragma unroll
    for (int nt = 0; nt < 4; nt++) {
      int n0 = 64 * w + 16 * nt + 4 * q;
      float4 bias = *(const float4*)&gb0[n0];
      uint2 o;
      o.x = pk_bf16(siluf_fast(acc[nt][0] + bias.x), siluf_fast(acc[nt][1] + bias.y));
      o.y = pk_bf16(siluf_fast(acc[nt][2] + bias.z), siluf_fast(acc[nt][3] + bias.w));
      *(uint2*)&x1s[m4 * LQ3 + n0] = o;
    }
  }
  __syncthreads();
  {  // L2: out 16 x 256, K=256
    v4f acc[4];
#pragma unroll
    for (int nt = 0; nt < 4; nt++) acc[nt] = z4;
    for (int kk = 0; kk < 8; kk++) {
      v8s bf = *(const v8s*)&x1s[m4 * LQ3 + 32 * kk + 8 * q];
#pragma unroll
      for (int nt = 0; nt < 4; nt++) {
        v8s wf = *(const v8s*)&G1F[(((4 * w + nt) * 8 + kk) * 64 + lane) * 8];
        acc[nt] = __builtin_amdgcn_mfma_f32_16x16x32_bf16(wf, bf, acc[nt], 0, 0, 0);
      }
    }
#pragma unroll
    for (int nt = 0; nt < 4; nt++) {
      int n0 = 64 * w + 16 * nt + 4 * q;
      float4 bias = *(const float4*)&gb1[n0];
      uint2 o;
      o.x = pk_bf16(siluf_fast(acc[nt][0] + bias.x), siluf_fast(acc[nt][1] + bias.y));
      o.y = pk_bf16(siluf_fast(acc[nt][2] + bias.z), siluf_fast(acc[nt][3] + bias.w));
      *(uint2*)&x2s[m4 * LQ3 + n0] = o;
    }
  }
  __syncthreads();
  {  // L3: out 16 x 64 (wave w: cols 16w..16w+15), K=256, linear + fold w/norm
    v4f acc = z4;
    for (int kk = 0; kk < 8; kk++) {
      v8s bf = *(const v8s*)&x2s[m4 * LQ3 + 32 * kk + 8 * q];
      v8s wf = *(const v8s*)&G2F[((w * 8 + kk) * 64 + lane) * 8];
      acc = __builtin_amdgcn_mfma_f32_16x16x32_bf16(wf, bf, acc, 0, 0, 0);
    }
    int p = p0 + m4;
    float wp = scal[(b * PSEL + p) * 8 + 4];
    float s2 = wp / sumw[b];
    int n0 = 16 * w + 4 * q;
    float4 bias = *(const float4*)&gb2[n0];
    float4 o;
    o.x = (acc[0] + bias.x) * s2;
    o.y = (acc[1] + bias.y) * s2;
    o.z = (acc[2] + bias.z) * s2;
    o.w = (acc[3] + bias.w) * s2;
    *(float4*)&gg[(b * PSEL + p) * 64 + n0] = o;
  }
}

// fused elem MLP via bf16 MFMA; grid (et, b, pc) so concurrent blocks share
// one pc-slice of A0 (512 KB working set -> L2-resident)
#define LP 136  // padded LDS row stride (bf16)
__global__ __launch_bounds__(256, 4) void k4_elem(
    const float* __restrict__ pb1, const float* __restrict__ pb2, char* ws) {
  int et = blockIdx.x, b = blockIdx.y, pc = blockIdx.z;
  int t = threadIdx.x;
  int lane = t & 63, w = t >> 6;
  int q = lane >> 4, m4 = lane & 15;
  const float* A0 = (const float*)(ws + WS_A0);
  const float* Ae = (const float*)(ws + WS_AE);
  const float* gg = (const float*)(ws + WS_GG);
  const unsigned short* W1F = (const unsigned short*)(ws + WS_W1F);
  const unsigned short* W2F = (const unsigned short*)(ws + WS_W2F);
  float* agg = (float*)(ws + WS_AGG);
  __shared__ __align__(16) unsigned short x0s[64 * LP];
  __shared__ __align__(16) unsigned short x1s[64 * LP];
  int e0 = et * 8;

  v8s w1f[2][4], w2f[4];
#pragma unroll
  for (int ct = 0; ct < 2; ct++)
#pragma unroll
    for (int kk = 0; kk < 4; kk++)
      w1f[ct][kk] = *(const v8s*)&W1F[(((2 * w + ct) * 4 + kk) * 64 + lane) * 8];
#pragma unroll
  for (int kk = 0; kk < 4; kk++)
    w2f[kk] = *(const v8s*)&W2F[(((w) * 4 + kk) * 64 + lane) * 8];
  float4 b1v[2];
  b1v[0] = *(const float4*)&pb1[32 * w + 4 * q];
  b1v[1] = *(const float4*)&pb1[32 * w + 16 + 4 * q];
  float4 b2v = *(const float4*)&pb2[16 * w + 4 * q];

  // phase-A constants: thread t covers (pl = t>>5, k0 = (t&31)*4, e = it)
  int pl = t >> 5, k0 = (t & 31) * 4;
  const float* a0p = A0 + (b * PSEL + pc * 64 + pl) * 128 + k0;  // +1024/g2
  const float* aep = Ae + e0 * 128 + k0;                          // +128/it
  unsigned short* xw = &x0s[pl * LP + k0];                        // +8*LP/it
  const float* ggp = gg + (b * PSEL + pc * 64 + (lane & 7)) * 64 + 16 * w + 4 * q;  // +512/g2

  v4f aggR[4];
  const v4f z4 = {0.f, 0.f, 0.f, 0.f};
#pragma unroll
  for (int mt = 0; mt < 4; mt++) aggR[mt] = z4;

  for (int g2 = 0; g2 < 8; g2++) {
    // phase A: x0s[8it+pl][k0..k0+3] = silu(A0[row] + Ae[e0+it]), bf16
    float4 a0v = *(const float4*)a0p;
#pragma unroll
    for (int it = 0; it < 8; it++) {
      float4 aev = *(const float4*)(aep + it * 128);
      uint2 o;
      o.x = pk_bf16(siluf_fast(a0v.x + aev.x), siluf_fast(a0v.y + aev.y));
      o.y = pk_bf16(siluf_fast(a0v.z + aev.z), siluf_fast(a0v.w + aev.w));
      *(uint2*)(xw + it * 8 * LP) = o;
    }
    a0p += 1024;
    __syncthreads();
    v4f acc1[4][2];
#pragma unroll
    for (int mt = 0; mt < 4; mt++) { acc1[mt][0] = z4; acc1[mt][1] = z4; }
#pragma unroll
    for (int kk = 0; kk < 4; kk++) {
#pragma unroll
      for (int mt = 0; mt < 4; mt++) {
        v8s bf = *(const v8s*)&x0s[(16 * mt + m4) * LP + 32 * kk + 8 * q];
        acc1[mt][0] = __builtin_amdgcn_mfma_f32_16x16x32_bf16(w1f[0][kk], bf, acc1[mt][0], 0, 0, 0);
        acc1[mt][1] = __builtin_amdgcn_mfma_f32_16x16x32_bf16(w1f[1][kk], bf, acc1[mt][1], 0, 0, 0);
      }
    }
#pragma unroll
    for (int mt = 0; mt < 4; mt++) {
#pragma unroll
      for (int ct = 0; ct < 2; ct++) {
        float4 bias = b1v[ct];
        uint2 o;
        o.x = pk_bf16(siluf_fast(acc1[mt][ct][0] + bias.x), siluf_fast(acc1[mt][ct][1] + bias.y));
        o.y = pk_bf16(siluf_fast(acc1[mt][ct][2] + bias.z), siluf_fast(acc1[mt][ct][3] + bias.w));
        int n0 = 32 * w + 16 * ct + 4 * q;
        *(uint2*)&x1s[(16 * mt + m4) * LP + n0] = o;
      }
    }
    __syncthreads();
    v4f acc2[4];
#pragma unroll
    for (int mt = 0; mt < 4; mt++) acc2[mt] = z4;
#pragma unroll
    for (int kk = 0; kk < 4; kk++) {
#pragma unroll
      for (int mt = 0; mt < 4; mt++) {
        v8s bf = *(const v8s*)&x1s[(16 * mt + m4) * LP + 32 * kk + 8 * q];
        acc2[mt] = __builtin_amdgcn_mfma_f32_16x16x32_bf16(w2f[kk], bf, acc2[mt], 0, 0, 0);
      }
    }
    float4 gv = *(const float4*)ggp;
    ggp += 512;
#pragma unroll
    for (int mt = 0; mt < 4; mt++) {
      aggR[mt][0] += gv.x * (acc2[mt][0] + b2v.x);
      aggR[mt][1] += gv.y * (acc2[mt][1] + b2v.y);
      aggR[mt][2] += gv.z * (acc2[mt][2] + b2v.z);
      aggR[mt][3] += gv.w * (acc2[mt][3] + b2v.w);
    }
  }
#pragma unroll
  for (int mt = 0; mt < 4; mt++) {
#pragma unroll
    for (int r = 0; r < 4; r++) {
      float v = aggR[mt][r];
      v += __shfl_xor(v, 1);
      v += __shfl_xor(v, 2);
      v += __shfl_xor(v, 4);
      if ((lane & 7) == 0) {
        int e = 2 * mt + ((lane >> 3) & 1);
        int n = 16 * w + 4 * q + r;
        atomicAdd(&agg[(b * NEL + e0 + e) * 64 + n], v);
      }
    }
  }
}

// output MLP 64->256 silu ->128 (f32 vector; small)
__global__ __launch_bounds__(256) void k5_out(
    const float* __restrict__ ow0, const float* __restrict__ ob0,
    const float* __restrict__ ow1, const float* __restrict__ ob1,
    const char* ws, float* __restrict__ out) {
  int row0 = blockIdx.x * 16;
  int t = threadIdx.x;
  const float* agg = (const float*)(ws + WS_AGG);
  __shared__ float xT[64][16];
  __shared__ float x1T[256][16];
  {
    int row = t & 15, fs = t >> 4;
    for (int f = fs; f < 64; f += 16) xT[f][row] = agg[(row0 + row) * 64 + f];
  }
  __syncthreads();
  {
    int r0 = (t & 3) * 4, c0 = (t >> 2) * 4;
    float acc[4][4] = {};
    for (int k2 = 0; k2 < 64; k2++) {
      float4 xv = *(const float4*)&xT[k2][r0];
      float4 wv = *(const float4*)&ow0[k2 * 256 + c0];
      float xs2[4] = {xv.x, xv.y, xv.z, xv.w};
      float wss[4] = {wv.x, wv.y, wv.z, wv.w};
#pragma unroll
      for (int i = 0; i < 4; i++)
#pragma unroll
        for (int j2 = 0; j2 < 4; j2++) acc[i][j2] += xs2[i] * wss[j2];
    }
#pragma unroll
    for (int jj = 0; jj < 4; jj++) {
      float bias = ob0[c0 + jj];
#pragma unroll
      for (int i = 0; i < 4; i++) x1T[c0 + jj][r0 + i] = siluf_fast(acc[i][jj] + bias);
    }
  }
  __syncthreads();
  {
    int r0 = (t & 3) * 4, c0 = (t >> 2) * 2;
    float acc[4][2] = {};
    for (int k2 = 0; k2 < 256; k2++) {
      float4 xv = *(const float4*)&x1T[k2][r0];
      float2 wv = *(const float2*)&ow1[k2 * 128 + c0];
      float xs2[4] = {xv.x, xv.y, xv.z, xv.w};
#pragma unroll
      for (int i = 0; i < 4; i++) {
        acc[i][0] += xs2[i] * wv.x;
        acc[i][1] += xs2[i] * wv.y;
      }
    }
#pragma unroll
    for (int i = 0; i < 4; i++)
#pragma unroll
      for (int j2 = 0; j2 < 2; j2++)
        out[(row0 + r0 + i) * 128 + c0 + j2] = acc[i][j2] + ob1[c0 + j2];
  }
}

extern "C" void kernel_launch(void* const* d_in, const int* in_sizes, int n_in,
                              void* d_out, int out_size, void* d_ws, size_t ws_size,
                              hipStream_t stream) {
  const float* h     = (const float*)d_in[0];
  const int*   z     = (const int*)d_in[1];
  const float* pos   = (const float*)d_in[2];
  const float* efeat = (const float*)d_in[4];
  const float* zemb  = (const float*)d_in[5];
  const float* pw0 = (const float*)d_in[6];
  const float* pb0 = (const float*)d_in[7];
  const float* pw1 = (const float*)d_in[8];
  const float* pb1 = (const float*)d_in[9];
  const float* pw2 = (const float*)d_in[10];
  const float* pb2 = (const float*)d_in[11];
  const float* gw0 = (const float*)d_in[12];
  const float* gb0 = (const float*)d_in[13];
  const float* gw1 = (const float*)d_in[14];
  const float* gb1 = (const float*)d_in[15];
  const float* gw2 = (const float*)d_in[16];
  const float* gb2 = (const float*)d_in[17];
  const float* ow0 = (const float*)d_in[18];
  const float* ob0 = (const float*)d_in[19];
  const float* ow1 = (const float*)d_in[20];
  const float* ob1 = (const float*)d_in[21];
  char* ws = (char*)d_ws;
  float* out = (float*)d_out;

  hipMemsetAsync(ws + WS_AGG, 0, NB * NEL * 64 * sizeof(float), stream);
  k_prep<<<864, 256, 0, stream>>>(z, efeat, pw0, pw1, pw2, gw0, gw1, gw2, ws);
  k1_select<<<16, 256, 0, stream>>>(pos, ws);
  k2b_a0<<<dim3(256, 16), 128, 0, stream>>>(z, zemb, pw0, pb0, ws);
  k3_geom<<<256, 256, 0, stream>>>(h, gb0, gb1, gb2, ws);
  k4_elem<<<dim3(16, 16, 4), 256, 0, stream>>>(pb1, pb2, ws);
  k5_out<<<128, 256, 0, stream>>>(ow0, ob0, ow1, ob1, ws, out);
}

// Round 6
// 215.990 us; speedup vs baseline: 3.3864x; 1.0628x over previous
//
#include <hip/hip_runtime.h>
#include <math.h>

#define NB 16
#define NA 64
#define NPAIR 2016
#define PSEL 256
#define NEL 128
// ws byte offsets (256-aligned)
#define WS_SUMW   0                      // [16] f32
#define WS_SELJ   2048                   // [4096] i32
#define WS_SELK   (WS_SELJ + 16384)
#define WS_SCAL   (WS_SELK + 16384)      // [4096][8] f32 (r0j,r0k,rjk,cos,w,zj,zk,-)
#define WS_AE     (WS_SCAL + 131072)     // [128][128] f32 (incl pb0)
#define WS_GG     (WS_AE + 65536)        // [4096][64] f32
#define WS_ZRJ    (WS_GG + 1048576)      // [91][128] f32
#define WS_ZRK    (WS_ZRJ + 47104)
#define WS_AGG    (WS_ZRK + 47104)       // [16][128][64] f32
#define WS_W1F    (WS_AGG + 524288)      // bf16 frag pw1, 32KB
#define WS_W2F    (WS_W1F + 32768)       // bf16 frag pw2, 16KB
#define WS_G0F    (WS_W2F + 16384)      // bf16 frag gw0 (K pad 384), 192KB
#define WS_G1F    (WS_G0F + 196608)      // bf16 frag gw1, 128KB
#define WS_G2F    (WS_G1F + 131072)      // bf16 frag gw2, 32KB

// prep index-space bounds (kA blocks 0..1466; k1-select blocks 1467..1482)
#define PREP_BLOCKS 1467
#define IDX_W1F  16384
#define IDX_W2F  24576
#define IDX_G0F  122880
#define IDX_G1F  188416
#define IDX_G2F  204800
#define IDX_AE   221184
#define IDX_ZRJ  232832
#define IDX_ZRK  244480
#define IDX_AGG  375552

typedef short v8s __attribute__((ext_vector_type(8)));
typedef float v4f __attribute__((ext_vector_type(4)));

__device__ __forceinline__ float siluf_fast(float x) {
  float e = __expf(-x);
  return x * __builtin_amdgcn_rcpf(1.0f + e);
}
__device__ __forceinline__ unsigned short f2bf(float f) {
  unsigned int u = __float_as_uint(f);
  return (unsigned short)((u + 0x7fffu + ((u >> 16) & 1u)) >> 16);
}
__device__ __forceinline__ unsigned int pk_bf16(float fa, float fb) {
  unsigned int ua = __float_as_uint(fa), ub = __float_as_uint(fb);
  ua = ua + 0x7fffu + ((ua >> 16) & 1u);
  ub = ub + 0x7fffu + ((ub >> 16) & 1u);
  return __builtin_amdgcn_perm(ub, ua, 0x07060302u);
}
__device__ __forceinline__ float cutf(float r) {
  return (r <= 6.0f) ? (0.5f * (cosf((3.14159265358979323846f * r) / 6.0f) + 1.0f)) : 0.0f;
}
__device__ __forceinline__ float rbff(float r, int i) {
  float rc = fminf(r, 6.0f);
  float c = (float)i * (6.0f / 31.0f);
  float d = rc - c;
  return expf(-26.694445f * d * d);
}
__device__ __forceinline__ void pair_jk(int p, int& j, int& k) {
  int jj = (int)((127.0 - sqrt(16129.0 - 8.0 * (double)p)) * 0.5);
  if (jj < 0) jj = 0;
  if (jj > 62) jj = 62;
  while (jj < 62 && (63 * (jj + 1) - ((jj + 1) * jj) / 2) <= p) jj++;
  while (jj > 0 && (63 * jj - (jj * (jj - 1)) / 2) > p) jj--;
  j = jj;
  k = p - (63 * jj - (jj * (jj - 1)) / 2) + jj + 1;
}

// ---- fused: weight-frag prep + Ae/zrow tables + AGG zero (blocks < PREP_BLOCKS)
//      + per-batch pair scoring / stable top-256 radix select (last 16 blocks)
__global__ __launch_bounds__(256) void kA(
    const int* __restrict__ z, const float* __restrict__ ef,
    const float* __restrict__ pos,
    const float* __restrict__ pw0, const float* __restrict__ pb0,
    const float* __restrict__ pw1, const float* __restrict__ pw2,
    const float* __restrict__ gw0, const float* __restrict__ gw1,
    const float* __restrict__ gw2, const float* __restrict__ zemb, char* ws) {
  __shared__ float px[64], py[64], pz[64], rr[64];
  __shared__ int hist[256], scan[256];
  __shared__ unsigned long long selk[256];
  __shared__ float wred[256];
  __shared__ unsigned long long s_pref, s_kstar;
  __shared__ int s_K, s_done, s_digit, s_exc, s_cnt;
  int blk = blockIdx.x, t = threadIdx.x;

  if (blk < PREP_BLOCKS) {
    int idx = blk * 256 + t;
    if (idx < IDX_W1F) {  // W1F: 128x128, NKK=4, A[n][k] frag order
      int j = idx & 7, l = (idx >> 3) & 63, t2 = idx >> 9;
      int kk = t2 & 3, nt = t2 >> 2;
      int n = 16 * nt + (l & 15), k = 32 * kk + (l >> 4) * 8 + j;
      ((unsigned short*)(ws + WS_W1F))[idx] = f2bf(pw1[k * 128 + n]);
    } else if (idx < IDX_W2F) {  // W2F: 128x64, NKK=4
      int id = idx - IDX_W1F;
      int j = id & 7, l = (id >> 3) & 63, t2 = id >> 9;
      int kk = t2 & 3, nt = t2 >> 2;
      int n = 16 * nt + (l & 15), k = 32 * kk + (l >> 4) * 8 + j;
      ((unsigned short*)(ws + WS_W2F))[id] = f2bf(pw2[k * 64 + n]);
    } else if (idx < IDX_G0F) {  // G0F: 353(->384)x256, NKK=12
      int id = idx - IDX_W2F;
      int j = id & 7, l = (id >> 3) & 63, t2 = id >> 9;
      int kk = t2 % 12, nt = t2 / 12;
      int n = 16 * nt + (l & 15), k = 32 * kk + (l >> 4) * 8 + j;
      float v = (k < 353) ? gw0[k * 256 + n] : 0.0f;
      ((unsigned short*)(ws + WS_G0F))[id] = f2bf(v);
    } else if (idx < IDX_G1F) {  // G1F: 256x256, NKK=8
      int id = idx - IDX_G0F;
      int j = id & 7, l = (id >> 3) & 63, t2 = id >> 9;
      int kk = t2 & 7, nt = t2 >> 3;
      int n = 16 * nt + (l & 15), k = 32 * kk + (l >> 4) * 8 + j;
      ((unsigned short*)(ws + WS_G1F))[id] = f2bf(gw1[k * 256 + n]);
    } else if (idx < IDX_G2F) {  // G2F: 256x64, NKK=8
      int id = idx - IDX_G1F;
      int j = id & 7, l = (id >> 3) & 63, t2 = id >> 9;
      int kk = t2 & 7, nt = t2 >> 3;
      int n = 16 * nt + (l & 15), k = 32 * kk + (l >> 4) * 8 + j;
      ((unsigned short*)(ws + WS_G2F))[id] = f2bf(gw2[k * 64 + n]);
    } else if (idx < IDX_AE) {  // Ae[e][d] = ef[e]@pw0[64:96] + pb0[d]
      int id = idx - IDX_G2F;
      int e = id >> 7, d = id & 127;
      float a = pb0[d];
      for (int i = 0; i < 32; i++) a += ef[e * 32 + i] * pw0[(64 + i) * 128 + d];
      ((float*)(ws + WS_AE))[e * 128 + d] = a;
    } else if (idx < IDX_ZRJ) {  // zrowJ[zv][d] = z_emb[zv]@pw0[0:32]
      int id = idx - IDX_AE;
      int zv = id >> 7, d = id & 127;
      float a = 0.0f;
      for (int i = 0; i < 32; i++) a += zemb[zv * 32 + i] * pw0[i * 128 + d];
      ((float*)(ws + WS_ZRJ))[id] = a;
    } else if (idx < IDX_ZRK) {  // zrowK[zv][d] = z_emb[zv]@pw0[32:64]
      int id = idx - IDX_ZRJ;
      int zv = id >> 7, d = id & 127;
      float a = 0.0f;
      for (int i = 0; i < 32; i++) a += zemb[zv * 32 + i] * pw0[(32 + i) * 128 + d];
      ((float*)(ws + WS_ZRK))[id] = a;
    } else if (idx < IDX_AGG) {  // zero AGG
      ((float*)(ws + WS_AGG))[idx - IDX_ZRK] = 0.0f;
    }
    return;
  }

  // ---- pair scoring + exact stable top-256 via 8-bit radix select on
  // 64-bit keys (score_bits<<32 | pair_idx); set identical to stable argsort.
  {
#pragma clang fp contract(off)
    int b = blk - PREP_BLOCKS;
    int is64 = (z[1] == 0) ? 1 : 0;
    if (t < 64) {
      px[t] = pos[(b * 64 + t) * 3 + 0];
      py[t] = pos[(b * 64 + t) * 3 + 1];
      pz[t] = pos[(b * 64 + t) * 3 + 2];
    }
    if (t == 0) { s_pref = 0; s_K = PSEL; s_done = 0; s_cnt = 0; }
    __syncthreads();
    if (t < 64) {
      float dx = px[t] - px[0], dy = py[t] - py[0], dz = pz[t] - pz[0];
      rr[t] = sqrtf((dx * dx + dy * dy) + dz * dz);
    }
    __syncthreads();
    unsigned long long keys[8];
#pragma unroll
    for (int ii = 0; ii < 8; ii++) {
      int p = t + 256 * ii;
      unsigned long long key = 0xFFFFFFFFFFFFFFFFull;
      if (p < NPAIR) {
        int j, k;
        pair_jk(p, j, k);
        bool vj = (j != 0) && (rr[j] <= 6.0f);
        bool vk = (rr[k] <= 6.0f);
        unsigned int sb = 0x7f800000u;
        if (vj && vk) {
          float dx = px[k] - px[j], dy = py[k] - py[j], dz = pz[k] - pz[j];
          float rjk = sqrtf((dx * dx + dy * dy) + dz * dz);
          float score = (rr[j] + rr[k]) + 0.5f * rjk;
          sb = __float_as_uint(score);
        }
        key = (((unsigned long long)sb) << 32) | (unsigned int)p;
      }
      keys[ii] = key;
    }
    for (int shift = 56; shift >= 0; shift -= 8) {
      if (s_done) break;
      hist[t] = 0;
      __syncthreads();
      unsigned long long hiMask = (shift == 56) ? 0ull : (~0ull << (shift + 8));
      unsigned long long pref = s_pref;
      int K = s_K;
#pragma unroll
      for (int ii = 0; ii < 8; ii++) {
        if ((keys[ii] & hiMask) == pref)
          atomicAdd(&hist[(int)((keys[ii] >> shift) & 255)], 1);
      }
      __syncthreads();
      scan[t] = hist[t];
      __syncthreads();
      for (int off = 1; off < 256; off <<= 1) {
        int add = (t >= off) ? scan[t - off] : 0;
        __syncthreads();
        scan[t] += add;
        __syncthreads();
      }
      int inc = scan[t], exc = inc - hist[t];
      if (exc < K && K <= inc) { s_digit = t; s_exc = exc; }
      __syncthreads();
      int d = s_digit, exc2 = s_exc, cnt = hist[d];
      unsigned long long npref = pref | ((unsigned long long)d << shift);
      if (cnt == 1) {
        unsigned long long inclMask = hiMask | (255ull << shift);
#pragma unroll
        for (int ii = 0; ii < 8; ii++)
          if ((keys[ii] & inclMask) == npref) s_kstar = keys[ii];
        if (t == 0) s_done = 1;
      } else if (shift == 0) {
        if (t == 0) { s_kstar = npref; s_done = 1; }
      } else {
        if (t == 0) { s_pref = npref; s_K = K - exc2; }
      }
      __syncthreads();
    }
    unsigned long long kstar = s_kstar;
#pragma unroll
    for (int ii = 0; ii < 8; ii++) {
      if (keys[ii] <= kstar) {
        int slot = atomicAdd(&s_cnt, 1);
        selk[slot] = keys[ii];
      }
    }
    __syncthreads();
    float myw = 0.0f;
    {
      unsigned long long key = selk[t];
      unsigned int sb = (unsigned int)(key >> 32);
      int p = (int)(key & 0xFFFFFFFFu);
      bool pv = (sb < 0x7f800000u);
      int j = 0, k = 0;
      if (pv) pair_jk(p, j, k);
      float r0j = rr[j], r0k = rr[k];
      float vjx = px[j] - px[0], vjy = py[j] - py[0], vjz = pz[j] - pz[0];
      float vkx = px[k] - px[0], vky = py[k] - py[0], vkz = pz[k] - pz[0];
      float dx = px[k] - px[j], dy = py[k] - py[j], dz = pz[k] - pz[j];
      float rjk = sqrtf((dx * dx + dy * dy) + dz * dz);
      float ij = 1.0f / fmaxf(r0j, 1e-8f);
      float ik = 1.0f / fmaxf(r0k, 1e-8f);
      float cs = (vjx * vkx + vjy * vky + vjz * vkz) * ij * ik;
      cs = fminf(1.0f, fmaxf(-1.0f, cs));
      float w = pv ? (cutf(r0j) * cutf(r0k) * cutf(rjk)) : 0.0f;
      int zj = is64 ? z[(b * 64 + j) * 2] : z[b * 64 + j];
      int zk = is64 ? z[(b * 64 + k) * 2] : z[b * 64 + k];
      int* selJ = (int*)(ws + WS_SELJ);
      int* selK = (int*)(ws + WS_SELK);
      float* scal = (float*)(ws + WS_SCAL);
      selJ[b * PSEL + t] = j;
      selK[b * PSEL + t] = k;
      float* s = &scal[(b * PSEL + t) * 8];
      s[0] = r0j; s[1] = r0k; s[2] = rjk; s[3] = cs; s[4] = w;
      ((int*)s)[5] = zj; ((int*)s)[6] = zk;
      myw = w;
    }
    wred[t] = myw;
    __syncthreads();
    for (int s2 = 128; s2 > 0; s2 >>= 1) {
      if (t < s2) wred[t] += wred[t + s2];
      __syncthreads();
    }
    if (t == 0) ((float*)(ws + WS_SUMW))[b] = fmaxf(wred[0], 1e-8f);
  }
}

// geom MLP via bf16 MFMA: 353(pad384)->256->256->64, folds w/sumw into gg
#define LP3 392
#define LQ3 264
__global__ __launch_bounds__(256) void k3_geom(const float* __restrict__ h,
    const float* __restrict__ gb0, const float* __restrict__ gb1,
    const float* __restrict__ gb2, char* ws) {
  int blk = blockIdx.x;
  int b = blk >> 4, p0 = (blk & 15) * 16;
  int t = threadIdx.x;
  int lane = t & 63, w = t >> 6;
  int q = lane >> 4, m4 = lane & 15;
  const int* selJ = (const int*)(ws + WS_SELJ);
  const int* selK = (const int*)(ws + WS_SELK);
  const float* scal = (const float*)(ws + WS_SCAL);
  const float* sumw = (const float*)(ws + WS_SUMW);
  float* gg = (float*)(ws + WS_GG);
  const unsigned short* G0F = (const unsigned short*)(ws + WS_G0F);
  const unsigned short* G1F = (const unsigned short*)(ws + WS_G1F);
  const unsigned short* G2F = (const unsigned short*)(ws + WS_G2F);
  __shared__ __align__(16) unsigned short xs[16 * LP3];
  __shared__ __align__(16) unsigned short x1s[16 * LQ3];
  __shared__ __align__(16) unsigned short x2s[16 * LQ3];
  const v4f z4 = {0.f, 0.f, 0.f, 0.f};
  {
    int row = t & 15, fs = t >> 4;
    int p = p0 + row;
    int j = selJ[b * PSEL + p], k = selK[b * PSEL + p];
    const float* s = &scal[(b * PSEL + p) * 8];
    float r0j = s[0], r0k = s[1], rjk = s[2], cs = s[3];
    for (int f = fs; f < 384; f += 16) {
      float v;
      if (f < 128) v = h[(b * 64 + j) * 128 + f];
      else if (f < 256) v = h[(b * 64 + k) * 128 + (f - 128)];
      else if (f < 288) v = rbff(r0j, f - 256);
      else if (f < 320) v = rbff(r0k, f - 288);
      else if (f < 352) v = rbff(rjk, f - 320);
      else if (f == 352) v = cs;
      else v = 0.0f;
      xs[row * LP3 + f] = f2bf(v);
    }
  }
  __syncthreads();
  {  // L1: out 16x256, K=384
    v4f acc[4];
#pragma unroll
    for (int nt = 0; nt < 4; nt++) acc[nt] = z4;
    for (int kk = 0; kk < 12; kk++) {
      v8s bf = *(const v8s*)&xs[m4 * LP3 + 32 * kk + 8 * q];
#pragma unroll
      for (int nt = 0; nt < 4; nt++) {
        v8s wf = *(const v8s*)&G0F[(((4 * w + nt) * 12 + kk) * 64 + lane) * 8];
        acc[nt] = __builtin_amdgcn_mfma_f32_16x16x32_bf16(wf, bf, acc[nt], 0, 0, 0);
      }
    }
#pragma unroll
    for (int nt = 0; nt < 4; nt++) {
      int n0 = 64 * w + 16 * nt + 4 * q;
      float4 bias = *(const float4*)&gb0[n0];
      uint2 o;
      o.x = pk_bf16(siluf_fast(acc[nt][0] + bias.x), siluf_fast(acc[nt][1] + bias.y));
      o.y = pk_bf16(siluf_fast(acc[nt][2] + bias.z), siluf_fast(acc[nt][3] + bias.w));
      *(uint2*)&x1s[m4 * LQ3 + n0] = o;
    }
  }
  __syncthreads();
  {  // L2: out 16x256, K=256
    v4f acc[4];
#pragma unroll
    for (int nt = 0; nt < 4; nt++) acc[nt] = z4;
    for (int kk = 0; kk < 8; kk++) {
      v8s bf = *(const v8s*)&x1s[m4 * LQ3 + 32 * kk + 8 * q];
#pragma unroll
      for (int nt = 0; nt < 4; nt++) {
        v8s wf = *(const v8s*)&G1F[(((4 * w + nt) * 8 + kk) * 64 + lane) * 8];
        acc[nt] = __builtin_amdgcn_mfma_f32_16x16x32_bf16(wf, bf, acc[nt], 0, 0, 0);
      }
    }
#pragma unroll
    for (int nt = 0; nt < 4; nt++) {
      int n0 = 64 * w + 16 * nt + 4 * q;
      float4 bias = *(const float4*)&gb1[n0];
      uint2 o;
      o.x = pk_bf16(siluf_fast(acc[nt][0] + bias.x), siluf_fast(acc[nt][1] + bias.y));
      o.y = pk_bf16(siluf_fast(acc[nt][2] + bias.z), siluf_fast(acc[nt][3] + bias.w));
      *(uint2*)&x2s[m4 * LQ3 + n0] = o;
    }
  }
  __syncthreads();
  {  // L3: out 16x64, K=256, linear + fold w/norm
    v4f acc = z4;
    for (int kk = 0; kk < 8; kk++) {
      v8s bf = *(const v8s*)&x2s[m4 * LQ3 + 32 * kk + 8 * q];
      v8s wf = *(const v8s*)&G2F[((w * 8 + kk) * 64 + lane) * 8];
      acc = __builtin_amdgcn_mfma_f32_16x16x32_bf16(wf, bf, acc, 0, 0, 0);
    }
    int p = p0 + m4;
    float wp = scal[(b * PSEL + p) * 8 + 4];
    float s2 = wp / sumw[b];
    int n0 = 16 * w + 4 * q;
    float4 bias = *(const float4*)&gb2[n0];
    float4 o;
    o.x = (acc[0] + bias.x) * s2;
    o.y = (acc[1] + bias.y) * s2;
    o.z = (acc[2] + bias.z) * s2;
    o.w = (acc[3] + bias.w) * s2;
    *(float4*)&gg[(b * PSEL + p) * 64 + n0] = o;
  }
}

// fused elem MLP via bf16 MFMA; A0 reconstructed on the fly from zrow tables
#define LP 136
__global__ __launch_bounds__(256, 4) void k4_elem(
    const float* __restrict__ pb1, const float* __restrict__ pb2, char* ws) {
  int et = blockIdx.x, b = blockIdx.y, pc = blockIdx.z;
  int t = threadIdx.x;
  int lane = t & 63, w = t >> 6;
  int q = lane >> 4, m4 = lane & 15;
  const float* Ae = (const float*)(ws + WS_AE);
  const float* gg = (const float*)(ws + WS_GG);
  const float* zrJ = (const float*)(ws + WS_ZRJ);
  const float* zrK = (const float*)(ws + WS_ZRK);
  const unsigned short* W1F = (const unsigned short*)(ws + WS_W1F);
  const unsigned short* W2F = (const unsigned short*)(ws + WS_W2F);
  float* agg = (float*)(ws + WS_AGG);
  __shared__ __align__(16) unsigned short x0s[64 * LP];
  __shared__ __align__(16) unsigned short x1s[64 * LP];
  int e0 = et * 8;

  v8s w1f[2][4], w2f[4];
#pragma unroll
  for (int ct = 0; ct < 2; ct++)
#pragma unroll
    for (int kk = 0; kk < 4; kk++)
      w1f[ct][kk] = *(const v8s*)&W1F[(((2 * w + ct) * 4 + kk) * 64 + lane) * 8];
#pragma unroll
  for (int kk = 0; kk < 4; kk++)
    w2f[kk] = *(const v8s*)&W2F[(((w) * 4 + kk) * 64 + lane) * 8];
  float4 b1v[2];
  b1v[0] = *(const float4*)&pb1[32 * w + 4 * q];
  b1v[1] = *(const float4*)&pb1[32 * w + 16 + 4 * q];
  float4 b2v = *(const float4*)&pb2[16 * w + 4 * q];

  // phase-A constants: thread t covers (pl = t>>5, k0 = (t&31)*4)
  int pl = t >> 5, k0 = (t & 31) * 4;
  const int* sI = (const int*)(ws + WS_SCAL) + (b * PSEL + pc * 64 + pl) * 8;
  const float* aep = Ae + e0 * 128 + k0;
  unsigned short* xw = &x0s[pl * LP + k0];
  const float* ggp = gg + (b * PSEL + pc * 64 + (lane & 7)) * 64 + 16 * w + 4 * q;

  v4f aggR[4];
  const v4f z4 = {0.f, 0.f, 0.f, 0.f};
#pragma unroll
  for (int mt = 0; mt < 4; mt++) aggR[mt] = z4;

  for (int g2 = 0; g2 < 8; g2++) {
    // phase A: x0s[8it+pl][k0..k0+3] = silu(zrJ[zj]+zrK[zk]+Ae[e0+it]), bf16
    int zj = sI[5], zk = sI[6];
    sI += 64;
    float4 aj = *(const float4*)&zrJ[zj * 128 + k0];
    float4 ak = *(const float4*)&zrK[zk * 128 + k0];
    float4 a0v;
    a0v.x = aj.x + ak.x; a0v.y = aj.y + ak.y;
    a0v.z = aj.z + ak.z; a0v.w = aj.w + ak.w;
#pragma unroll
    for (int it = 0; it < 8; it++) {
      float4 aev = *(const float4*)(aep + it * 128);
      uint2 o;
      o.x = pk_bf16(siluf_fast(a0v.x + aev.x), siluf_fast(a0v.y + aev.y));
      o.y = pk_bf16(siluf_fast(a0v.z + aev.z), siluf_fast(a0v.w + aev.w));
      *(uint2*)(xw + it * 8 * LP) = o;
    }
    __syncthreads();
    v4f acc1[4][2];
#pragma unroll
    for (int mt = 0; mt < 4; mt++) { acc1[mt][0] = z4; acc1[mt][1] = z4; }
#pragma unroll
    for (int kk = 0; kk < 4; kk++) {
#pragma unroll
      for (int mt = 0; mt < 4; mt++) {
        v8s bf = *(const v8s*)&x0s[(16 * mt + m4) * LP + 32 * kk + 8 * q];
        acc1[mt][0] = __builtin_amdgcn_mfma_f32_16x16x32_bf16(w1f[0][kk], bf, acc1[mt][0], 0, 0, 0);
        acc1[mt][1] = __builtin_amdgcn_mfma_f32_16x16x32_bf16(w1f[1][kk], bf, acc1[mt][1], 0, 0, 0);
      }
    }
#pragma unroll
    for (int mt = 0; mt < 4; mt++) {
#pragma unroll
      for (int ct = 0; ct < 2; ct++) {
        float4 bias = b1v[ct];
        uint2 o;
        o.x = pk_bf16(siluf_fast(acc1[mt][ct][0] + bias.x), siluf_fast(acc1[mt][ct][1] + bias.y));
        o.y = pk_bf16(siluf_fast(acc1[mt][ct][2] + bias.z), siluf_fast(acc1[mt][ct][3] + bias.w));
        int n0 = 32 * w + 16 * ct + 4 * q;
        *(uint2*)&x1s[(16 * mt + m4) * LP + n0] = o;
      }
    }
    __syncthreads();
    v4f acc2[4];
#pragma unroll
    for (int mt = 0; mt < 4; mt++) acc2[mt] = z4;
#pragma unroll
    for (int kk = 0; kk < 4; kk++) {
#pragma unroll
      for (int mt = 0; mt < 4; mt++) {
        v8s bf = *(const v8s*)&x1s[(16 * mt + m4) * LP + 32 * kk + 8 * q];
        acc2[mt] = __builtin_amdgcn_mfma_f32_16x16x32_bf16(w2f[kk], bf, acc2[mt], 0, 0, 0);
      }
    }
    float4 gv = *(const float4*)ggp;
    ggp += 512;
#pragma unroll
    for (int mt = 0; mt < 4; mt++) {
      aggR[mt][0] += gv.x * (acc2[mt][0] + b2v.x);
      aggR[mt][1] += gv.y * (acc2[mt][1] + b2v.y);
      aggR[mt][2] += gv.z * (acc2[mt][2] + b2v.z);
      aggR[mt][3] += gv.w * (acc2[mt][3] + b2v.w);
    }
  }
#pragma unroll
  for (int mt = 0; mt < 4; mt++) {
#pragma unroll
    for (int r = 0; r < 4; r++) {
      float v = aggR[mt][r];
      v += __shfl_xor(v, 1);
      v += __shfl_xor(v, 2);
      v += __shfl_xor(v, 4);
      if ((lane & 7) == 0) {
        int e = 2 * mt + ((lane >> 3) & 1);
        int n = 16 * w + 4 * q + r;
        atomicAdd(&agg[(b * NEL + e0 + e) * 64 + n], v);
      }
    }
  }
}

// output MLP 64->256 silu ->128
__global__ __launch_bounds__(256) void k5_out(
    const float* __restrict__ ow0, const float* __restrict__ ob0,
    const float* __restrict__ ow1, const float* __restrict__ ob1,
    const char* ws, float* __restrict__ out) {
  int row0 = blockIdx.x * 16;
  int t = threadIdx.x;
  const float* agg = (const float*)(ws + WS_AGG);
  __shared__ float xT[64][16];
  __shared__ float x1T[256][16];
  {
    int row = t & 15, fs = t >> 4;
    for (int f = fs; f < 64; f += 16) xT[f][row] = agg[(row0 + row) * 64 + f];
  }
  __syncthreads();
  {
    int r0 = (t & 3) * 4, c0 = (t >> 2) * 4;
    float acc[4][4] = {};
    for (int k2 = 0; k2 < 64; k2++) {
      float4 xv = *(const float4*)&xT[k2][r0];
      float4 wv = *(const float4*)&ow0[k2 * 256 + c0];
      float xs2[4] = {xv.x, xv.y, xv.z, xv.w};
      float wss[4] = {wv.x, wv.y, wv.z, wv.w};
#pragma unroll
      for (int i = 0; i < 4; i++)
#pragma unroll
        for (int j2 = 0; j2 < 4; j2++) acc[i][j2] += xs2[i] * wss[j2];
    }
#pragma unroll
    for (int jj = 0; jj < 4; jj++) {
      float bias = ob0[c0 + jj];
#pragma unroll
      for (int i = 0; i < 4; i++) x1T[c0 + jj][r0 + i] = siluf_fast(acc[i][jj] + bias);
    }
  }
  __syncthreads();
  {
    int r0 = (t & 3) * 4, c0 = (t >> 2) * 2;
    float acc[4][2] = {};
    for (int k2 = 0; k2 < 256; k2++) {
      float4 xv = *(const float4*)&x1T[k2][r0];
      float2 wv = *(const float2*)&ow1[k2 * 128 + c0];
      float xs2[4] = {xv.x, xv.y, xv.z, xv.w};
#pragma unroll
      for (int i = 0; i < 4; i++) {
        acc[i][0] += xs2[i] * wv.x;
        acc[i][1] += xs2[i] * wv.y;
      }
    }
#pragma unroll
    for (int i = 0; i < 4; i++)
#pragma unroll
      for (int j2 = 0; j2 < 2; j2++)
        out[(row0 + r0 + i) * 128 + c0 + j2] = acc[i][j2] + ob1[c0 + j2];
  }
}

extern "C" void kernel_launch(void* const* d_in, const int* in_sizes, int n_in,
                              void* d_out, int out_size, void* d_ws, size_t ws_size,
                              hipStream_t stream) {
  const float* h     = (const float*)d_in[0];
  const int*   z     = (const int*)d_in[1];
  const float* pos   = (const float*)d_in[2];
  const float* efeat = (const float*)d_in[4];
  const float* zemb  = (const float*)d_in[5];
  const float* pw0 = (const float*)d_in[6];
  const float* pb0 = (const float*)d_in[7];
  const float* pw1 = (const float*)d_in[8];
  const float* pb1 = (const float*)d_in[9];
  const float* pw2 = (const float*)d_in[10];
  const float* pb2 = (const float*)d_in[11];
  const float* gw0 = (const float*)d_in[12];
  const float* gb0 = (const float*)d_in[13];
  const float* gw1 = (const float*)d_in[14];
  const float* gb1 = (const float*)d_in[15];
  const float* gw2 = (const float*)d_in[16];
  const float* gb2 = (const float*)d_in[17];
  const float* ow0 = (const float*)d_in[18];
  const float* ob0 = (const float*)d_in[19];
  const float* ow1 = (const float*)d_in[20];
  const float* ob1 = (const float*)d_in[21];
  char* ws = (char*)d_ws;
  float* out = (float*)d_out;

  kA<<<PREP_BLOCKS + 16, 256, 0, stream>>>(z, efeat, pos, pw0, pb0, pw1, pw2,
                                           gw0, gw1, gw2, zemb, ws);
  k3_geom<<<256, 256, 0, stream>>>(h, gb0, gb1, gb2, ws);
  k4_elem<<<dim3(16, 16, 4), 256, 0, stream>>>(pb1, pb2, ws);
  k5_out<<<128, 256, 0, stream>>>(ow0, ob0, ow1, ob1, ws, out);
}